// Round 17
// baseline (155.778 us; speedup 1.0000x reference)
//
#include <hip/hip_runtime.h>
#include <hip/hip_bf16.h>
#include <math.h>

typedef unsigned short u16;
typedef unsigned int u32;
typedef __attribute__((ext_vector_type(8))) short frag8;   // 8 x bf16 (4 VGPR)
typedef __attribute__((ext_vector_type(4))) short short4v; // 4 x bf16
typedef __attribute__((ext_vector_type(4))) float facc4;   // 16x16 MFMA accumulator
typedef __attribute__((ext_vector_type(16))) float facc16; // 32x32 MFMA accumulator
typedef __attribute__((ext_vector_type(2))) int v2i;
typedef __attribute__((ext_vector_type(4))) int i4;

typedef __attribute__((address_space(3))) void lds_void;
typedef const __attribute__((address_space(1))) void gbl_void;

__device__ __forceinline__ void gload16(const void* g, void* l) {
  __builtin_amdgcn_global_load_lds((gbl_void*)g, (lds_void*)l, 16, 0, 0);
}

__device__ __forceinline__ u16 f2bf(float f) {
  union { float f; unsigned u; } v; v.f = f;
  unsigned r = v.u + 0x7FFFu + ((v.u >> 16) & 1u);   // RNE
  return (u16)(r >> 16);
}

__device__ __forceinline__ u16 f2bf_hw(float f) {
  __hip_bfloat16 h = __float2bfloat16(f);
  return *(u16*)&h;
}

__device__ __forceinline__ facc4 mfma16(frag8 a, frag8 b, facc4 c) {
  return __builtin_amdgcn_mfma_f32_16x16x32_bf16(a, b, c, 0, 0, 0);
}
__device__ __forceinline__ facc16 mfma32(frag8 a, frag8 b, facc16 c) {
  return __builtin_amdgcn_mfma_f32_32x32x16_bf16(a, b, c, 0, 0, 0);
}
__device__ __forceinline__ v2i pl32swap(int x, int y) {
  return __builtin_amdgcn_permlane32_swap(x, y, false, false);
}
__device__ __forceinline__ float vmax3(float a, float b, float c) {
  float d;
  asm("v_max3_f32 %0, %1, %2, %3" : "=v"(d) : "v"(a), "v"(b), "v"(c));
  return d;
}
__device__ __forceinline__ u32 cvtpk(float lo, float hi) {   // lo->bits[15:0], hi->bits[31:16]
  u32 r;
  asm("v_cvt_pk_bf16_f32 %0, %1, %2" : "=v"(r) : "v"(lo), "v"(hi));
  return r;
}

// ---------------- fused prep: weights cvt + LoRA xa + x cvt + mask cvt/swizzle ----
// blocks [0,1536): wi->bf16; [1536,2048): wo->bf16; [2048,3072): k_xa;
// [3072,7168): mask fp32 -> bf16 pre-swizzled rows.
__global__ __launch_bounds__(256) void k_prep(
    const float* __restrict__ wi, u16* __restrict__ w_bf,
    const float* __restrict__ wo, u16* __restrict__ wo_bf,
    const float* __restrict__ x, const float* __restrict__ la,
    float* __restrict__ xa, u16* __restrict__ xb,
    const float* __restrict__ m, u16* __restrict__ mb) {
  const int blk = blockIdx.x;
  if (blk < 2048) {
    const float* in; u16* out; int i;
    if (blk < 1536) { in = wi; out = w_bf; i = (blk * 256 + threadIdx.x) * 8; }
    else { in = wo; out = wo_bf; i = ((blk - 1536) * 256 + threadIdx.x) * 8; }
    float4 a = *(const float4*)(in + i);
    float4 b = *(const float4*)(in + i + 4);
    frag8 o;
    o[0] = (short)f2bf(a.x); o[1] = (short)f2bf(a.y);
    o[2] = (short)f2bf(a.z); o[3] = (short)f2bf(a.w);
    o[4] = (short)f2bf(b.x); o[5] = (short)f2bf(b.y);
    o[6] = (short)f2bf(b.z); o[7] = (short)f2bf(b.w);
    *(frag8*)(out + i) = o;
  } else if (blk < 3072) {
    const int row = (blk - 2048) * 4 + (threadIdx.x >> 6);
    const int lane = threadIdx.x & 63;
    const float* xr = x + (size_t)row * 1024;
    float s[8];
#pragma unroll
    for (int j = 0; j < 8; ++j) s[j] = 0.f;
    for (int c = lane * 4; c < 1024; c += 256) {
      float4 xv = *(const float4*)(xr + c);
      short4v o;
      o[0] = (short)f2bf(xv.x); o[1] = (short)f2bf(xv.y);
      o[2] = (short)f2bf(xv.z); o[3] = (short)f2bf(xv.w);
      *(short4v*)(xb + (size_t)row * 1024 + c) = o;
#pragma unroll
      for (int j = 0; j < 8; ++j) {
        float4 av = *(const float4*)(la + j * 1024 + c);
        s[j] += xv.x * av.x + xv.y * av.y + xv.z * av.z + xv.w * av.w;
      }
    }
#pragma unroll
    for (int j = 0; j < 8; ++j) {
#pragma unroll
      for (int m_ = 1; m_ < 64; m_ <<= 1) s[j] += __shfl_xor(s[j], m_);
    }
    if (lane == 0) {
#pragma unroll
      for (int j = 0; j < 8; ++j) xa[(size_t)row * 8 + j] = s[j];
    }
  } else {
    const int row = blk - 3072;           // b*2048 + q
    const int q = row & 2047;
    const int t = threadIdx.x;
    const int T = t >> 3, c = t & 7;
    const float* src = m + (size_t)row * 2048 + T * 64 + c * 8;
    float4 a = *(const float4*)src;
    float4 b = *(const float4*)(src + 4);
    u32 g0a = cvtpk(a.x, a.y), g0b = cvtpk(a.z, a.w);
    u32 g1a = cvtpk(b.x, b.y), g1b = cvtpk(b.z, b.w);
    i4 o;
    if (q & 1) { o[0] = (int)g1a; o[1] = (int)g1b; o[2] = (int)g0a; o[3] = (int)g0b; }
    else       { o[0] = (int)g0a; o[1] = (int)g0b; o[2] = (int)g1a; o[3] = (int)g1b; }
    const int cp = c ^ ((q & 15) >> 1);
    *(i4*)(mb + (size_t)row * 2048 + T * 64 + cp * 8) = o;
  }
}

// ---------------- QKV GEMM: [4096,1024]x[3072,1024]^T + bias + LoRA ----------------
// q,k written [B,H,S,D]; V written TRANSPOSED [B,H,D,S] via LDS-transposed
// coalesced epilogue (k_vt fused away; As/Bs aliased as the transpose tile).
__global__ __launch_bounds__(256) void k_gemm_qkv(
    const u16* __restrict__ A, const u16* __restrict__ B,
    const float* __restrict__ bias, const float* __restrict__ xa,
    const float* __restrict__ lb,
    u16* __restrict__ qw, u16* __restrict__ kw, u16* __restrict__ vw) {
  __shared__ __align__(16) u16 smem[2 * 128 * 64];   // As | Bs, reused as T[128][128]
  u16* As = smem;
  u16* Bs = smem + 128 * 64;
  const int mbase = blockIdx.y * 128;
  const int nbase = blockIdx.x * 128;
  const int t = threadIdx.x;
  const int lane = t & 63;
  const int w = t >> 6;
  const int wm = w >> 1, wn = w & 1;
  const facc4 vzero = {0.f, 0.f, 0.f, 0.f};
  facc4 acc[4][4];
#pragma unroll
  for (int i = 0; i < 4; ++i)
#pragma unroll
    for (int j = 0; j < 4; ++j) acc[i][j] = vzero;

  for (int kt = 0; kt < 16; ++kt) {
    __syncthreads();
#pragma unroll
    for (int i = 0; i < 4; ++i) {
      int c = i * 256 + t;
      int row = c >> 3, cs = c & 7;
      int scs = cs ^ (row & 7);                 // pre-swizzled global source
      gload16(A + (size_t)(mbase + row) * 1024 + kt * 64 + scs * 8,
              As + (size_t)(i * 256 + w * 64) * 8);
      gload16(B + (size_t)(nbase + row) * 1024 + kt * 64 + scs * 8,
              Bs + (size_t)(i * 256 + w * 64) * 8);
    }
    __syncthreads();
#pragma unroll
    for (int ks = 0; ks < 2; ++ks) {
      frag8 af[4], bfr[4];
#pragma unroll
      for (int mi = 0; mi < 4; ++mi) {
        int row = wm * 64 + mi * 16 + (lane & 15);
        int off = (ks * 64 + ((lane >> 4) << 4)) ^ ((row & 7) << 4);
        af[mi] = *(const frag8*)((const char*)As + row * 128 + off);
      }
#pragma unroll
      for (int ni = 0; ni < 4; ++ni) {
        int row = wn * 64 + ni * 16 + (lane & 15);
        int off = (ks * 64 + ((lane >> 4) << 4)) ^ ((row & 7) << 4);
        bfr[ni] = *(const frag8*)((const char*)Bs + row * 128 + off);
      }
#pragma unroll
      for (int mi = 0; mi < 4; ++mi)
#pragma unroll
        for (int ni = 0; ni < 4; ++ni)
          acc[mi][ni] = mfma16(af[mi], bfr[ni], acc[mi][ni]);
    }
  }
  // epilogue: bias + LoRA(fp32) + split/scale
  const int which = nbase >> 10;
  const int r0 = (lane >> 4) << 2;
  float bi_[4]; float4 lb0_[4], lb1_[4]; int hh[4], dd[4];
#pragma unroll
  for (int ni = 0; ni < 4; ++ni) {
    const int gc = nbase + wn * 64 + ni * 16 + (lane & 15);
    bi_[ni] = bias[gc];
    lb0_[ni] = *(const float4*)(lb + (size_t)gc * 8);
    lb1_[ni] = *(const float4*)(lb + (size_t)gc * 8 + 4);
    const int e = gc & 1023;
    hh[ni] = e >> 6; dd[ni] = e & 63;
  }
  if (which != 2) {
    // Q/K: direct [B,H,S,D] scatter (d consecutive across 16 lanes -> 32B runs)
#pragma unroll
    for (int mi = 0; mi < 4; ++mi) {
#pragma unroll
      for (int r = 0; r < 4; ++r) {
        const int gr = mbase + wm * 64 + mi * 16 + r0 + r;
        const float4 xa0 = *(const float4*)(xa + (size_t)gr * 8);
        const float4 xa1 = *(const float4*)(xa + (size_t)gr * 8 + 4);
        const int bb = gr >> 11, s = gr & 2047;
        const size_t rbase = ((size_t)(bb * 16) * 2048 + (size_t)s) * 64;
#pragma unroll
        for (int ni = 0; ni < 4; ++ni) {
          float v = acc[mi][ni][r] + bi_[ni]
                  + xa0.x * lb0_[ni].x + xa0.y * lb0_[ni].y + xa0.z * lb0_[ni].z + xa0.w * lb0_[ni].w
                  + xa1.x * lb1_[ni].x + xa1.y * lb1_[ni].y + xa1.z * lb1_[ni].z + xa1.w * lb1_[ni].w;
          const size_t idx = rbase + (size_t)hh[ni] * (2048 * 64) + dd[ni];
          if (which == 0) qw[idx] = f2bf(v * 0.125f);
          else            kw[idx] = f2bf(v);
        }
      }
    }
  } else {
    // V: transpose in LDS (T[e][s], XOR-swizzled rows), then coalesced [B,H,D,S] store
    __syncthreads();          // all waves done reading As/Bs
#pragma unroll
    for (int mi = 0; mi < 4; ++mi) {
#pragma unroll
      for (int r = 0; r < 4; ++r) {
        const int rowl = wm * 64 + mi * 16 + r0 + r;   // s-local 0..127
        const int gr = mbase + rowl;
        const float4 xa0 = *(const float4*)(xa + (size_t)gr * 8);
        const float4 xa1 = *(const float4*)(xa + (size_t)gr * 8 + 4);
#pragma unroll
        for (int ni = 0; ni < 4; ++ni) {
          float v = acc[mi][ni][r] + bi_[ni]
                  + xa0.x * lb0_[ni].x + xa0.y * lb0_[ni].y + xa0.z * lb0_[ni].z + xa0.w * lb0_[ni].w
                  + xa1.x * lb1_[ni].x + xa1.y * lb1_[ni].y + xa1.z * lb1_[ni].z + xa1.w * lb1_[ni].w;
          const int col = wn * 64 + ni * 16 + (lane & 15);   // e-local 0..127
          smem[col * 128 + (rowl ^ ((col & 15) << 3))] = f2bf(v);
        }
      }
    }
    __syncthreads();
    // store: wave w covers cols [32w,32w+32); per iter 4 cols x 16 s-chunks of 8
    const int bb = mbase >> 11, s0 = mbase & 2047;
    const int ebase = nbase - 2048;
#pragma unroll
    for (int it = 0; it < 8; ++it) {
      const int col = w * 32 + it * 4 + (lane >> 4);
      const int chunk = lane & 15;
      const int prow = (chunk * 8) ^ ((col & 15) << 3);
      frag8 val = *(const frag8*)(smem + col * 128 + prow);
      const int e = ebase + col, h = e >> 6, d = e & 63;
      *(frag8*)(vw + ((size_t)(bb * 16 + h) * 64 + d) * 2048 + s0 + chunk * 8) = val;
    }
  }
}

// ---------------- flash attention (swapped QK^T, in-register softmax) ----------------
// q,k: [B,H,S,D] bf16 (q pre-scaled); vt: [B,H,D,S] bf16; mb: bf16 swizzled mask
// out: [B,S,H*D] bf16. 4 waves x 32 q-rows; KVBLK 64; 32x32x16 MFMA.
// ONE barrier + ONE vmcnt(0) per tile: KV staged AFTER barrier (prev compute done
// implies prev reads consumed); Ms restaged wave-privately (each wave stages only
// the 32 rows it reads, after consuming them). Grid XCD-partitioned.
__global__ __launch_bounds__(256, 3) void k_attn(
    const u16* __restrict__ qw, const u16* __restrict__ kw,
    const u16* __restrict__ vt, const u16* __restrict__ mb,
    u16* __restrict__ ao_out) {
  __shared__ __align__(16) u16 Ks[2][64 * 64];    // [kv][d] rows 128B, XOR-swizzled
  __shared__ __align__(16) u16 Vs[2][64 * 64];    // [d][kv] rows 128B, XOR-swizzled
  __shared__ __align__(16) u16 Ms[128 * 64];      // [q][kv] bf16, granule-swizzled
  const int id = blockIdx.x;
  const int xcd = id & 7;
  const int r_ = id >> 3;
  const int qt = r_ & 15;
  const int bh = xcd * 4 + (r_ >> 4);             // 4 heads per XCD, same b per XCD
  const int b = bh >> 4, hd = bh & 15;
  const int t = threadIdx.x, lane = t & 63, w = t >> 6;
  const int l31 = lane & 31, hh = lane >> 5;
  const int q = qt * 128 + w * 32 + l31;
  const size_t hoff = (size_t)bh * (2048 * 64);
  const float L2E = 1.44269504088896341f;

  frag8 qf[4];
  {
    const u16* qp = qw + hoff + (size_t)q * 64 + hh * 8;
#pragma unroll
    for (int dk = 0; dk < 4; ++dk) qf[dk] = *(const frag8*)(qp + dk * 16);
  }
  const u16* mrowb = mb + (size_t)(b * 2048 + qt * 128) * 2048;   // block mask base

  // hoisted LDS byte offsets (loop-invariant)
  int koff[8], voff[8], moff[8];
#pragma unroll
  for (int kb = 0; kb < 2; ++kb) {
    int row = kb * 32 + l31, sw = (row & 7) << 4;
#pragma unroll
    for (int dk = 0; dk < 4; ++dk)
      koff[kb * 4 + dk] = row * 128 + ((dk * 32 + hh * 16) ^ sw);
  }
#pragma unroll
  for (int km = 0; km < 4; ++km)
#pragma unroll
    for (int nd = 0; nd < 2; ++nd) {
      int row = nd * 32 + l31, sw = (row & 7) << 4;
      voff[km * 2 + nd] = row * 128 + ((km * 32 + hh * 16) ^ sw);
    }
  {
    int rowq = w * 32 + l31, msw = rowq & 15;
#pragma unroll
    for (int kb = 0; kb < 2; ++kb)
#pragma unroll
      for (int rg2 = 0; rg2 < 4; ++rg2)
        moff[kb * 4 + rg2] = rowq * 128 + ((((kb * 4 + rg2) * 2 + hh) ^ msw) * 8);
  }

  float mrun = -__builtin_inff(), lrun = 0.f;
  facc16 oacc[2];
#pragma unroll
  for (int nd = 0; nd < 2; ++nd)
#pragma unroll
    for (int rg = 0; rg < 16; ++rg) oacc[nd][rg] = 0.f;

  // stage K/V tile: 2 K + 2 V = 4 gload16 per thread (cooperative, barrier-guarded)
  auto STAGE_KV = [&](int buf, int tile) {
    const int kv0 = tile * 64;
#pragma unroll
    for (int i = 0; i < 2; ++i) {
      int c = i * 256 + t;
      int r = c >> 3, cc = c & 7;
      int sc = cc ^ (r & 7);
      gload16(kw + hoff + (size_t)(kv0 + r) * 64 + sc * 8, (char*)&Ks[buf][0] + c * 16);
      gload16(vt + hoff + (size_t)r * 2048 + kv0 + sc * 8, (char*)&Vs[buf][0] + c * 16);
    }
  };
  // stage mask: WAVE-PRIVATE — wave w stages exactly its own rows [32w, 32w+32)
  auto STAGE_M = [&](int tile) {
    const int kv0 = tile * 64;
#pragma unroll
    for (int i = 0; i < 4; ++i) {
      int c = i * 64 + lane;
      int row = w * 32 + (c >> 3), ch = c & 7;
      gload16(mrowb + (size_t)row * 2048 + kv0 + ch * 8,
              (char*)&Ms[0] + w * 4096 + c * 16);
    }
  };

  STAGE_KV(0, 0);
  STAGE_M(0);

  typedef union { facc16 v; float4 f[4]; } ZU;

  for (int tt = 0; tt < 32; ++tt) {
    const int cur = tt & 1;
    // KV(tt)+M(tt) were issued one full tile ago -> this drain is ~free
    asm volatile("s_waitcnt vmcnt(0)" ::: "memory");
    __builtin_amdgcn_s_barrier();     // all waves: tile tt visible AND tt-1 compute done
    if (tt + 1 < 32) STAGE_KV(cur ^ 1, tt + 1);   // safe: buf last read in tt-1

    // mask from LDS -> C-in (bf16 unpack by shift/mask)
    const char* msb = (const char*)&Ms[0];
    ZU z[2];
#pragma unroll
    for (int kb = 0; kb < 2; ++kb)
#pragma unroll
      for (int rg2 = 0; rg2 < 4; ++rg2) {
        v2i m2 = *(const v2i*)(msb + moff[kb * 4 + rg2]);
        z[kb].v[rg2 * 4 + 0] = __int_as_float(m2.x << 16);
        z[kb].v[rg2 * 4 + 1] = __int_as_float(m2.x & 0xFFFF0000);
        z[kb].v[rg2 * 4 + 2] = __int_as_float(m2.y << 16);
        z[kb].v[rg2 * 4 + 3] = __int_as_float(m2.y & 0xFFFF0000);
      }

    // S^T = K Q^T + mask : lane holds S[k][q] for its q = l31
    const char* ksb = (const char*)&Ks[0][0] + cur * 8192;
    __builtin_amdgcn_s_setprio(1);
#pragma unroll
    for (int kb = 0; kb < 2; ++kb)
#pragma unroll
      for (int dk = 0; dk < 4; ++dk) {
        frag8 kf = *(const frag8*)(ksb + koff[kb * 4 + dk]);
        z[kb].v = mfma32(kf, qf[dk], z[kb].v);
      }
    __builtin_amdgcn_s_setprio(0);
    // restage mask for tt+1: this wave's Ms/K ds_reads are consumed by now
    if (tt + 1 < 32) STAGE_M(tt + 1);

    // row max: max3 tree over 32 values, then one permlane32_swap
    float tm;
    {
      const facc16& a = z[0].v; const facc16& c = z[1].v;
      float g0 = vmax3(a[0], a[1], a[2]);
      float g1 = vmax3(a[3], a[4], a[5]);
      float g2 = vmax3(a[6], a[7], a[8]);
      float g3 = vmax3(a[9], a[10], a[11]);
      float g4 = vmax3(a[12], a[13], a[14]);
      float g5 = vmax3(a[15], c[0], c[1]);
      float g6 = vmax3(c[2], c[3], c[4]);
      float g7 = vmax3(c[5], c[6], c[7]);
      float g8 = vmax3(c[8], c[9], c[10]);
      float g9 = vmax3(c[11], c[12], c[13]);
      float h0 = vmax3(g0, g1, g2);
      float h1 = vmax3(g3, g4, g5);
      float h2 = vmax3(g6, g7, g8);
      float h3 = vmax3(g9, c[14], c[15]);
      float t0 = vmax3(h0, h1, h2);
      tm = fmaxf(t0, h3);
      v2i r = pl32swap(__float_as_int(tm), __float_as_int(tm));
      tm = fmaxf(__int_as_float(r.x), __int_as_float(r.y));
    }
    // deferred rescale (cold path)
    if (__any(tm > mrun + 8.f)) {
      float nm = fmaxf(mrun, tm);
      float sc = exp2f((mrun - nm) * L2E);
      mrun = nm; lrun *= sc;
#pragma unroll
      for (int rg = 0; rg < 16; ++rg) {
        int q_r = (rg & 3) + 8 * (rg >> 2) + 4 * hh;
        float scq = __int_as_float(__builtin_amdgcn_ds_bpermute(q_r << 2, __float_as_int(sc)));
        oacc[0][rg] *= scq; oacc[1][rg] *= scq;
      }
    }
    // exp + row-sum + pack (cvt_pk)
    const float mL = mrun * L2E;
    float ps0 = 0.f, ps1 = 0.f, ps2 = 0.f, ps3 = 0.f;
    u32 u[2][4][2];
#pragma unroll
    for (int kb = 0; kb < 2; ++kb)
#pragma unroll
      for (int rg2 = 0; rg2 < 4; ++rg2) {
        float pp0 = exp2f(__builtin_fmaf(z[kb].v[rg2 * 4 + 0], L2E, -mL));
        float pp1 = exp2f(__builtin_fmaf(z[kb].v[rg2 * 4 + 1], L2E, -mL));
        float pp2 = exp2f(__builtin_fmaf(z[kb].v[rg2 * 4 + 2], L2E, -mL));
        float pp3 = exp2f(__builtin_fmaf(z[kb].v[rg2 * 4 + 3], L2E, -mL));
        ps0 += pp0; ps1 += pp1; ps2 += pp2; ps3 += pp3;
        u[kb][rg2][0] = cvtpk(pp0, pp1);
        u[kb][rg2][1] = cvtpk(pp2, pp3);
      }
    float ps = (ps0 + ps1) + (ps2 + ps3);
    {
      v2i r = pl32swap(__float_as_int(ps), __float_as_int(ps));
      ps = __int_as_float(r.x) + __int_as_float(r.y);
    }
    lrun += ps;
    // PV: redistribute P via permlane32_swap into A-frags, mfma against Vs
    const char* vsb = (const char*)&Vs[0][0] + cur * 8192;
    __builtin_amdgcn_s_setprio(1);
#pragma unroll
    for (int km = 0; km < 4; ++km) {
      const int kb = km >> 1, j = km & 1;
      v2i s0 = pl32swap(u[kb][2 * j][0], u[kb][2 * j + 1][0]);
      v2i s1 = pl32swap(u[kb][2 * j][1], u[kb][2 * j + 1][1]);
      i4 pw = { s0.x, s1.x, s0.y, s1.y };
      frag8 pf = *(frag8*)&pw;
#pragma unroll
      for (int nd = 0; nd < 2; ++nd) {
        frag8 vf = *(const frag8*)(vsb + voff[km * 2 + nd]);
        oacc[nd] = mfma32(pf, vf, oacc[nd]);
      }
    }
    __builtin_amdgcn_s_setprio(0);
    // no barrier B: next iteration's barrier A provides the only sync needed
  }
  // epilogue: normalize + store [B,S,E] bf16
  float linv = 1.0f / lrun;
#pragma unroll
  for (int rg = 0; rg < 16; ++rg) {
    int q_r = (rg & 3) + 8 * (rg >> 2) + 4 * hh;
    float lq = __int_as_float(__builtin_amdgcn_ds_bpermute(q_r << 2, __float_as_int(linv)));
    int gq = qt * 128 + w * 32 + q_r;
    size_t rowoff = (size_t)(b * 2048 + gq) * 1024 + hd * 64;
#pragma unroll
    for (int nd = 0; nd < 2; ++nd)
      ao_out[rowoff + nd * 32 + l31] = f2bf_hw(oacc[nd][rg] * lq);
  }
}

// ---------------- out proj GEMM: [4096,1024]x[1024,1024]^T + bias -> fp32 ----------------
// BM=64 tiles -> 512 blocks (2/CU), LDS 24KB, acc[2][4] per wave.
__global__ __launch_bounds__(256) void k_gemm_out(
    const u16* __restrict__ A, const u16* __restrict__ B,
    const float* __restrict__ bias, float* __restrict__ out) {
  __shared__ __align__(16) u16 As[64 * 64];
  __shared__ __align__(16) u16 Bs[128 * 64];
  const int mbase = blockIdx.y * 64;
  const int nbase = blockIdx.x * 128;
  const int t = threadIdx.x;
  const int lane = t & 63;
  const int w = t >> 6;
  const int wm = w >> 1, wn = w & 1;
  const facc4 vzero = {0.f, 0.f, 0.f, 0.f};
  facc4 acc[2][4];
#pragma unroll
  for (int i = 0; i < 2; ++i)
#pragma unroll
    for (int j = 0; j < 4; ++j) acc[i][j] = vzero;

  for (int kt = 0; kt < 16; ++kt) {
    __syncthreads();
#pragma unroll
    for (int i = 0; i < 2; ++i) {
      int c = i * 256 + t;
      int row = c >> 3, cs = c & 7;
      int scs = cs ^ (row & 7);
      gload16(A + (size_t)(mbase + row) * 1024 + kt * 64 + scs * 8,
              As + (size_t)(i * 256 + w * 64) * 8);
    }
#pragma unroll
    for (int i = 0; i < 4; ++i) {
      int c = i * 256 + t;
      int row = c >> 3, cs = c & 7;
      int scs = cs ^ (row & 7);
      gload16(B + (size_t)(nbase + row) * 1024 + kt * 64 + scs * 8,
              Bs + (size_t)(i * 256 + w * 64) * 8);
    }
    __syncthreads();
#pragma unroll
    for (int ks = 0; ks < 2; ++ks) {
      frag8 af[2], bfr[4];
#pragma unroll
      for (int mi = 0; mi < 2; ++mi) {
        int row = wm * 32 + mi * 16 + (lane & 15);
        int off = (ks * 64 + ((lane >> 4) << 4)) ^ ((row & 7) << 4);
        af[mi] = *(const frag8*)((const char*)As + row * 128 + off);
      }
#pragma unroll
      for (int ni = 0; ni < 4; ++ni) {
        int row = wn * 64 + ni * 16 + (lane & 15);
        int off = (ks * 64 + ((lane >> 4) << 4)) ^ ((row & 7) << 4);
        bfr[ni] = *(const frag8*)((const char*)Bs + row * 128 + off);
      }
#pragma unroll
      for (int mi = 0; mi < 2; ++mi)
#pragma unroll
        for (int ni = 0; ni < 4; ++ni)
          acc[mi][ni] = mfma16(af[mi], bfr[ni], acc[mi][ni]);
    }
  }
  const int r0 = (lane >> 4) << 2;
#pragma unroll
  for (int ni = 0; ni < 4; ++ni) {
    const int gc = nbase + wn * 64 + ni * 16 + (lane & 15);
    const float bi = bias[gc];
#pragma unroll
    for (int mi = 0; mi < 2; ++mi)
#pragma unroll
      for (int r = 0; r < 4; ++r) {
        const int gr = mbase + wm * 32 + mi * 16 + r0 + r;
        out[(size_t)gr * 1024 + gc] = acc[mi][ni][r] + bi;
      }
  }
}

extern "C" void kernel_launch(void* const* d_in, const int* in_sizes, int n_in,
                              void* d_out, int out_size, void* d_ws, size_t ws_size,
                              hipStream_t stream) {
  const float* x    = (const float*)d_in[0];
  const float* mask = (const float*)d_in[1];
  const float* wi   = (const float*)d_in[2];
  const float* bi   = (const float*)d_in[3];
  const float* wo   = (const float*)d_in[4];
  const float* bo   = (const float*)d_in[5];
  const float* la   = (const float*)d_in[6];
  const float* lb   = (const float*)d_in[7];
  float* out = (float*)d_out;

  char* ws = (char*)d_ws;
  u16* x_bf  = (u16*)ws;              ws += (size_t)4096 * 1024 * 2;
  u16* w_bf  = (u16*)ws;              ws += (size_t)3072 * 1024 * 2;
  u16* wo_bf = (u16*)ws;              ws += (size_t)1024 * 1024 * 2;
  u16* q_ws  = (u16*)ws;              ws += (size_t)4096 * 1024 * 2;
  u16* k_ws  = (u16*)ws;              ws += (size_t)4096 * 1024 * 2;
  u16* v_t   = (u16*)ws;              ws += (size_t)4096 * 1024 * 2;
  u16* a_ws  = (u16*)ws;              ws += (size_t)4096 * 1024 * 2;
  u16* m_bf  = (u16*)ws;              ws += (size_t)4096 * 2048 * 2;
  float* xa  = (float*)ws;            ws += (size_t)4096 * 8 * 4;

  k_prep<<<dim3(7168), dim3(256), 0, stream>>>(wi, w_bf, wo, wo_bf,
                                               x, la, xa, x_bf, mask, m_bf);
  k_gemm_qkv<<<dim3(24, 32), dim3(256), 0, stream>>>(x_bf, w_bf, bi, xa, lb,
                                                     q_ws, k_ws, v_t);
  k_attn<<<dim3(512), dim3(256), 0, stream>>>(q_ws, k_ws, v_t, m_bf, a_ws);
  k_gemm_out<<<dim3(8, 64), dim3(256), 0, stream>>>(a_ws, wo_bf, bo, out);
}

// Round 18
// 152.113 us; speedup vs baseline: 1.0241x; 1.0241x over previous
//
#include <hip/hip_runtime.h>
#include <hip/hip_bf16.h>
#include <math.h>

typedef unsigned short u16;
typedef unsigned int u32;
typedef __attribute__((ext_vector_type(8))) short frag8;   // 8 x bf16 (4 VGPR)
typedef __attribute__((ext_vector_type(4))) short short4v; // 4 x bf16
typedef __attribute__((ext_vector_type(4))) float facc4;   // 16x16 MFMA accumulator
typedef __attribute__((ext_vector_type(16))) float facc16; // 32x32 MFMA accumulator
typedef __attribute__((ext_vector_type(2))) int v2i;
typedef __attribute__((ext_vector_type(4))) int i4;

typedef __attribute__((address_space(3))) void lds_void;
typedef const __attribute__((address_space(1))) void gbl_void;

__device__ __forceinline__ void gload16(const void* g, void* l) {
  __builtin_amdgcn_global_load_lds((gbl_void*)g, (lds_void*)l, 16, 0, 0);
}

__device__ __forceinline__ u16 f2bf(float f) {
  union { float f; unsigned u; } v; v.f = f;
  unsigned r = v.u + 0x7FFFu + ((v.u >> 16) & 1u);   // RNE
  return (u16)(r >> 16);
}

__device__ __forceinline__ u16 f2bf_hw(float f) {
  __hip_bfloat16 h = __float2bfloat16(f);
  return *(u16*)&h;
}

__device__ __forceinline__ facc4 mfma16(frag8 a, frag8 b, facc4 c) {
  return __builtin_amdgcn_mfma_f32_16x16x32_bf16(a, b, c, 0, 0, 0);
}
__device__ __forceinline__ facc16 mfma32(frag8 a, frag8 b, facc16 c) {
  return __builtin_amdgcn_mfma_f32_32x32x16_bf16(a, b, c, 0, 0, 0);
}
__device__ __forceinline__ v2i pl32swap(int x, int y) {
  return __builtin_amdgcn_permlane32_swap(x, y, false, false);
}
__device__ __forceinline__ float vmax3(float a, float b, float c) {
  float d;
  asm("v_max3_f32 %0, %1, %2, %3" : "=v"(d) : "v"(a), "v"(b), "v"(c));
  return d;
}
__device__ __forceinline__ u32 cvtpk(float lo, float hi) {   // lo->bits[15:0], hi->bits[31:16]
  u32 r;
  asm("v_cvt_pk_bf16_f32 %0, %1, %2" : "=v"(r) : "v"(lo), "v"(hi));
  return r;
}

// ---------------- fused prep: weights cvt + LoRA xa + x cvt + mask cvt/swizzle ----
// blocks [0,1536): wi->bf16; [1536,2048): wo->bf16; [2048,3072): k_xa;
// [3072,7168): mask fp32 -> bf16 pre-swizzled rows.
__global__ __launch_bounds__(256) void k_prep(
    const float* __restrict__ wi, u16* __restrict__ w_bf,
    const float* __restrict__ wo, u16* __restrict__ wo_bf,
    const float* __restrict__ x, const float* __restrict__ la,
    float* __restrict__ xa, u16* __restrict__ xb,
    const float* __restrict__ m, u16* __restrict__ mb) {
  const int blk = blockIdx.x;
  if (blk < 2048) {
    const float* in; u16* out; int i;
    if (blk < 1536) { in = wi; out = w_bf; i = (blk * 256 + threadIdx.x) * 8; }
    else { in = wo; out = wo_bf; i = ((blk - 1536) * 256 + threadIdx.x) * 8; }
    float4 a = *(const float4*)(in + i);
    float4 b = *(const float4*)(in + i + 4);
    frag8 o;
    o[0] = (short)f2bf(a.x); o[1] = (short)f2bf(a.y);
    o[2] = (short)f2bf(a.z); o[3] = (short)f2bf(a.w);
    o[4] = (short)f2bf(b.x); o[5] = (short)f2bf(b.y);
    o[6] = (short)f2bf(b.z); o[7] = (short)f2bf(b.w);
    *(frag8*)(out + i) = o;
  } else if (blk < 3072) {
    const int row = (blk - 2048) * 4 + (threadIdx.x >> 6);
    const int lane = threadIdx.x & 63;
    const float* xr = x + (size_t)row * 1024;
    float s[8];
#pragma unroll
    for (int j = 0; j < 8; ++j) s[j] = 0.f;
    for (int c = lane * 4; c < 1024; c += 256) {
      float4 xv = *(const float4*)(xr + c);
      short4v o;
      o[0] = (short)f2bf(xv.x); o[1] = (short)f2bf(xv.y);
      o[2] = (short)f2bf(xv.z); o[3] = (short)f2bf(xv.w);
      *(short4v*)(xb + (size_t)row * 1024 + c) = o;
#pragma unroll
      for (int j = 0; j < 8; ++j) {
        float4 av = *(const float4*)(la + j * 1024 + c);
        s[j] += xv.x * av.x + xv.y * av.y + xv.z * av.z + xv.w * av.w;
      }
    }
#pragma unroll
    for (int j = 0; j < 8; ++j) {
#pragma unroll
      for (int m_ = 1; m_ < 64; m_ <<= 1) s[j] += __shfl_xor(s[j], m_);
    }
    if (lane == 0) {
#pragma unroll
      for (int j = 0; j < 8; ++j) xa[(size_t)row * 8 + j] = s[j];
    }
  } else {
    const int row = blk - 3072;           // b*2048 + q
    const int q = row & 2047;
    const int t = threadIdx.x;
    const int T = t >> 3, c = t & 7;
    const float* src = m + (size_t)row * 2048 + T * 64 + c * 8;
    float4 a = *(const float4*)src;
    float4 b = *(const float4*)(src + 4);
    u32 g0a = cvtpk(a.x, a.y), g0b = cvtpk(a.z, a.w);
    u32 g1a = cvtpk(b.x, b.y), g1b = cvtpk(b.z, b.w);
    i4 o;
    if (q & 1) { o[0] = (int)g1a; o[1] = (int)g1b; o[2] = (int)g0a; o[3] = (int)g0b; }
    else       { o[0] = (int)g0a; o[1] = (int)g0b; o[2] = (int)g1a; o[3] = (int)g1b; }
    const int cp = c ^ ((q & 15) >> 1);
    *(i4*)(mb + (size_t)row * 2048 + T * 64 + cp * 8) = o;
  }
}

// ---------------- QKV GEMM: [4096,1024]x[3072,1024]^T + bias + LoRA ----------------
// q,k written [B,H,S,D]; V written TRANSPOSED [B,H,D,S] via LDS-transposed
// coalesced epilogue (k_vt fused away; As/Bs aliased as the transpose tile).
__global__ __launch_bounds__(256) void k_gemm_qkv(
    const u16* __restrict__ A, const u16* __restrict__ B,
    const float* __restrict__ bias, const float* __restrict__ xa,
    const float* __restrict__ lb,
    u16* __restrict__ qw, u16* __restrict__ kw, u16* __restrict__ vw) {
  __shared__ __align__(16) u16 smem[2 * 128 * 64];   // As | Bs, reused as T[128][128]
  u16* As = smem;
  u16* Bs = smem + 128 * 64;
  const int mbase = blockIdx.y * 128;
  const int nbase = blockIdx.x * 128;
  const int t = threadIdx.x;
  const int lane = t & 63;
  const int w = t >> 6;
  const int wm = w >> 1, wn = w & 1;
  const facc4 vzero = {0.f, 0.f, 0.f, 0.f};
  facc4 acc[4][4];
#pragma unroll
  for (int i = 0; i < 4; ++i)
#pragma unroll
    for (int j = 0; j < 4; ++j) acc[i][j] = vzero;

  for (int kt = 0; kt < 16; ++kt) {
    __syncthreads();
#pragma unroll
    for (int i = 0; i < 4; ++i) {
      int c = i * 256 + t;
      int row = c >> 3, cs = c & 7;
      int scs = cs ^ (row & 7);                 // pre-swizzled global source
      gload16(A + (size_t)(mbase + row) * 1024 + kt * 64 + scs * 8,
              As + (size_t)(i * 256 + w * 64) * 8);
      gload16(B + (size_t)(nbase + row) * 1024 + kt * 64 + scs * 8,
              Bs + (size_t)(i * 256 + w * 64) * 8);
    }
    __syncthreads();
#pragma unroll
    for (int ks = 0; ks < 2; ++ks) {
      frag8 af[4], bfr[4];
#pragma unroll
      for (int mi = 0; mi < 4; ++mi) {
        int row = wm * 64 + mi * 16 + (lane & 15);
        int off = (ks * 64 + ((lane >> 4) << 4)) ^ ((row & 7) << 4);
        af[mi] = *(const frag8*)((const char*)As + row * 128 + off);
      }
#pragma unroll
      for (int ni = 0; ni < 4; ++ni) {
        int row = wn * 64 + ni * 16 + (lane & 15);
        int off = (ks * 64 + ((lane >> 4) << 4)) ^ ((row & 7) << 4);
        bfr[ni] = *(const frag8*)((const char*)Bs + row * 128 + off);
      }
#pragma unroll
      for (int mi = 0; mi < 4; ++mi)
#pragma unroll
        for (int ni = 0; ni < 4; ++ni)
          acc[mi][ni] = mfma16(af[mi], bfr[ni], acc[mi][ni]);
    }
  }
  // epilogue: bias + LoRA(fp32) + split/scale
  const int which = nbase >> 10;
  const int r0 = (lane >> 4) << 2;
  float bi_[4]; float4 lb0_[4], lb1_[4]; int hh[4], dd[4];
#pragma unroll
  for (int ni = 0; ni < 4; ++ni) {
    const int gc = nbase + wn * 64 + ni * 16 + (lane & 15);
    bi_[ni] = bias[gc];
    lb0_[ni] = *(const float4*)(lb + (size_t)gc * 8);
    lb1_[ni] = *(const float4*)(lb + (size_t)gc * 8 + 4);
    const int e = gc & 1023;
    hh[ni] = e >> 6; dd[ni] = e & 63;
  }
  if (which != 2) {
    // Q/K: direct [B,H,S,D] scatter (d consecutive across 16 lanes -> 32B runs)
#pragma unroll
    for (int mi = 0; mi < 4; ++mi) {
#pragma unroll
      for (int r = 0; r < 4; ++r) {
        const int gr = mbase + wm * 64 + mi * 16 + r0 + r;
        const float4 xa0 = *(const float4*)(xa + (size_t)gr * 8);
        const float4 xa1 = *(const float4*)(xa + (size_t)gr * 8 + 4);
        const int bb = gr >> 11, s = gr & 2047;
        const size_t rbase = ((size_t)(bb * 16) * 2048 + (size_t)s) * 64;
#pragma unroll
        for (int ni = 0; ni < 4; ++ni) {
          float v = acc[mi][ni][r] + bi_[ni]
                  + xa0.x * lb0_[ni].x + xa0.y * lb0_[ni].y + xa0.z * lb0_[ni].z + xa0.w * lb0_[ni].w
                  + xa1.x * lb1_[ni].x + xa1.y * lb1_[ni].y + xa1.z * lb1_[ni].z + xa1.w * lb1_[ni].w;
          const size_t idx = rbase + (size_t)hh[ni] * (2048 * 64) + dd[ni];
          if (which == 0) qw[idx] = f2bf(v * 0.125f);
          else            kw[idx] = f2bf(v);
        }
      }
    }
  } else {
    // V: transpose in LDS (T[e][s], XOR-swizzled rows), then coalesced [B,H,D,S] store
    __syncthreads();          // all waves done reading As/Bs
#pragma unroll
    for (int mi = 0; mi < 4; ++mi) {
#pragma unroll
      for (int r = 0; r < 4; ++r) {
        const int rowl = wm * 64 + mi * 16 + r0 + r;   // s-local 0..127
        const int gr = mbase + rowl;
        const float4 xa0 = *(const float4*)(xa + (size_t)gr * 8);
        const float4 xa1 = *(const float4*)(xa + (size_t)gr * 8 + 4);
#pragma unroll
        for (int ni = 0; ni < 4; ++ni) {
          float v = acc[mi][ni][r] + bi_[ni]
                  + xa0.x * lb0_[ni].x + xa0.y * lb0_[ni].y + xa0.z * lb0_[ni].z + xa0.w * lb0_[ni].w
                  + xa1.x * lb1_[ni].x + xa1.y * lb1_[ni].y + xa1.z * lb1_[ni].z + xa1.w * lb1_[ni].w;
          const int col = wn * 64 + ni * 16 + (lane & 15);   // e-local 0..127
          smem[col * 128 + (rowl ^ ((col & 15) << 3))] = f2bf(v);
        }
      }
    }
    __syncthreads();
    // store: wave w covers cols [32w,32w+32); per iter 4 cols x 16 s-chunks of 8
    const int bb = mbase >> 11, s0 = mbase & 2047;
    const int ebase = nbase - 2048;
#pragma unroll
    for (int it = 0; it < 8; ++it) {
      const int col = w * 32 + it * 4 + (lane >> 4);
      const int chunk = lane & 15;
      const int prow = (chunk * 8) ^ ((col & 15) << 3);
      frag8 val = *(const frag8*)(smem + col * 128 + prow);
      const int e = ebase + col, h = e >> 6, d = e & 63;
      *(frag8*)(vw + ((size_t)(bb * 16 + h) * 64 + d) * 2048 + s0 + chunk * 8) = val;
    }
  }
}

// ---------------- flash attention (swapped QK^T, in-register softmax) ----------------
// q,k: [B,H,S,D] bf16 (q pre-scaled); vt: [B,H,D,S] bf16; mb: bf16 swizzled mask
// out: [B,S,H*D] bf16. 4 waves x 32 q-rows; KVBLK 64; 32x32x16 MFMA.
// Grid: 1-D 512, XCD-partitioned (each head's K/V L2-resident in one XCD).
// Ms SINGLE-buffered -> LDS 48KB; launch_bounds(256,3).
__global__ __launch_bounds__(256, 3) void k_attn(
    const u16* __restrict__ qw, const u16* __restrict__ kw,
    const u16* __restrict__ vt, const u16* __restrict__ mb,
    u16* __restrict__ ao_out) {
  __shared__ __align__(16) u16 Ks[2][64 * 64];    // [kv][d] rows 128B, XOR-swizzled
  __shared__ __align__(16) u16 Vs[2][64 * 64];    // [d][kv] rows 128B, XOR-swizzled
  __shared__ __align__(16) u16 Ms[128 * 64];      // [q][kv] bf16, granule-swizzled
  const int id = blockIdx.x;
  const int xcd = id & 7;
  const int r_ = id >> 3;
  const int qt = r_ & 15;
  const int bh = xcd * 4 + (r_ >> 4);             // 4 heads per XCD, same b per XCD
  const int b = bh >> 4, hd = bh & 15;
  const int t = threadIdx.x, lane = t & 63, w = t >> 6;
  const int l31 = lane & 31, hh = lane >> 5;
  const int q = qt * 128 + w * 32 + l31;
  const size_t hoff = (size_t)bh * (2048 * 64);
  const float L2E = 1.44269504088896341f;

  frag8 qf[4];
  {
    const u16* qp = qw + hoff + (size_t)q * 64 + hh * 8;
#pragma unroll
    for (int dk = 0; dk < 4; ++dk) qf[dk] = *(const frag8*)(qp + dk * 16);
  }
  const u16* mrowb = mb + (size_t)(b * 2048 + qt * 128) * 2048;   // block mask base

  // hoisted LDS byte offsets (loop-invariant)
  int koff[8], voff[8], moff[8];
#pragma unroll
  for (int kb = 0; kb < 2; ++kb) {
    int row = kb * 32 + l31, sw = (row & 7) << 4;
#pragma unroll
    for (int dk = 0; dk < 4; ++dk)
      koff[kb * 4 + dk] = row * 128 + ((dk * 32 + hh * 16) ^ sw);
  }
#pragma unroll
  for (int km = 0; km < 4; ++km)
#pragma unroll
    for (int nd = 0; nd < 2; ++nd) {
      int row = nd * 32 + l31, sw = (row & 7) << 4;
      voff[km * 2 + nd] = row * 128 + ((km * 32 + hh * 16) ^ sw);
    }
  {
    int rowq = w * 32 + l31, msw = rowq & 15;
#pragma unroll
    for (int kb = 0; kb < 2; ++kb)
#pragma unroll
      for (int rg2 = 0; rg2 < 4; ++rg2)
        moff[kb * 4 + rg2] = rowq * 128 + ((((kb * 4 + rg2) * 2 + hh) ^ msw) * 8);
  }

  float mrun = -__builtin_inff(), lrun = 0.f;
  facc16 oacc[2];
#pragma unroll
  for (int nd = 0; nd < 2; ++nd)
#pragma unroll
    for (int rg = 0; rg < 16; ++rg) oacc[nd][rg] = 0.f;

  // stage K/V tile: 2 K + 2 V = 4 gload16 per thread
  auto STAGE_KV = [&](int buf, int tile) {
    const int kv0 = tile * 64;
#pragma unroll
    for (int i = 0; i < 2; ++i) {
      int c = i * 256 + t;
      int r = c >> 3, cc = c & 7;
      int sc = cc ^ (r & 7);
      gload16(kw + hoff + (size_t)(kv0 + r) * 64 + sc * 8, (char*)&Ks[buf][0] + c * 16);
      gload16(vt + hoff + (size_t)r * 2048 + kv0 + sc * 8, (char*)&Vs[buf][0] + c * 16);
    }
  };
  // stage mask tile into the single Ms buffer: 4 gload16 per thread
  auto STAGE_M = [&](int tile) {
    const int kv0 = tile * 64;
#pragma unroll
    for (int i = 0; i < 4; ++i) {
      int c = i * 256 + t;
      int row = c >> 3, ch = c & 7;
      gload16(mrowb + (size_t)row * 2048 + kv0 + ch * 8, (char*)&Ms[0] + c * 16);
    }
  };

  STAGE_KV(0, 0);
  STAGE_M(0);

  typedef union { facc16 v; float4 f[4]; } ZU;

  for (int tt = 0; tt < 32; ++tt) {
    const int cur = tt & 1;
    if (tt + 1 < 32) {
      STAGE_KV(cur ^ 1, tt + 1);                 // 4 loads in flight past the wait
      asm volatile("s_waitcnt vmcnt(4)" ::: "memory");   // KV(tt)+M(tt) landed
    } else {
      asm volatile("s_waitcnt vmcnt(0)" ::: "memory");
    }
    __builtin_amdgcn_s_barrier();                // A: Ks/Vs[cur] + Ms(tt) visible

    // mask from LDS -> C-in (bf16 unpack by shift/mask)
    const char* msb = (const char*)&Ms[0];
    ZU z[2];
#pragma unroll
    for (int kb = 0; kb < 2; ++kb)
#pragma unroll
      for (int rg2 = 0; rg2 < 4; ++rg2) {
        v2i m2 = *(const v2i*)(msb + moff[kb * 4 + rg2]);
        z[kb].v[rg2 * 4 + 0] = __int_as_float(m2.x << 16);
        z[kb].v[rg2 * 4 + 1] = __int_as_float(m2.x & 0xFFFF0000);
        z[kb].v[rg2 * 4 + 2] = __int_as_float(m2.y << 16);
        z[kb].v[rg2 * 4 + 3] = __int_as_float(m2.y & 0xFFFF0000);
      }

    // S^T = K Q^T + mask : lane holds S[k][q] for its q = l31
    const char* ksb = (const char*)&Ks[0][0] + cur * 8192;
    __builtin_amdgcn_s_setprio(1);
#pragma unroll
    for (int kb = 0; kb < 2; ++kb)
#pragma unroll
      for (int dk = 0; dk < 4; ++dk) {
        frag8 kf = *(const frag8*)(ksb + koff[kb * 4 + dk]);
        z[kb].v = mfma32(kf, qf[dk], z[kb].v);
      }
    __builtin_amdgcn_s_setprio(0);

    // row max: max3 tree over 32 values, then one permlane32_swap
    float tm;
    {
      const facc16& a = z[0].v; const facc16& c = z[1].v;
      float g0 = vmax3(a[0], a[1], a[2]);
      float g1 = vmax3(a[3], a[4], a[5]);
      float g2 = vmax3(a[6], a[7], a[8]);
      float g3 = vmax3(a[9], a[10], a[11]);
      float g4 = vmax3(a[12], a[13], a[14]);
      float g5 = vmax3(a[15], c[0], c[1]);
      float g6 = vmax3(c[2], c[3], c[4]);
      float g7 = vmax3(c[5], c[6], c[7]);
      float g8 = vmax3(c[8], c[9], c[10]);
      float g9 = vmax3(c[11], c[12], c[13]);
      float h0 = vmax3(g0, g1, g2);
      float h1 = vmax3(g3, g4, g5);
      float h2 = vmax3(g6, g7, g8);
      float h3 = vmax3(g9, c[14], c[15]);
      float t0 = vmax3(h0, h1, h2);
      tm = fmaxf(t0, h3);
      v2i r = pl32swap(__float_as_int(tm), __float_as_int(tm));
      tm = fmaxf(__int_as_float(r.x), __int_as_float(r.y));
    }
    // deferred rescale (cold path)
    if (__any(tm > mrun + 8.f)) {
      float nm = fmaxf(mrun, tm);
      float sc = exp2f((mrun - nm) * L2E);
      mrun = nm; lrun *= sc;
#pragma unroll
      for (int rg = 0; rg < 16; ++rg) {
        int q_r = (rg & 3) + 8 * (rg >> 2) + 4 * hh;
        float scq = __int_as_float(__builtin_amdgcn_ds_bpermute(q_r << 2, __float_as_int(sc)));
        oacc[0][rg] *= scq; oacc[1][rg] *= scq;
      }
    }
    // exp + row-sum + pack (cvt_pk)
    const float mL = mrun * L2E;
    float ps0 = 0.f, ps1 = 0.f, ps2 = 0.f, ps3 = 0.f;
    u32 u[2][4][2];
#pragma unroll
    for (int kb = 0; kb < 2; ++kb)
#pragma unroll
      for (int rg2 = 0; rg2 < 4; ++rg2) {
        float pp0 = exp2f(__builtin_fmaf(z[kb].v[rg2 * 4 + 0], L2E, -mL));
        float pp1 = exp2f(__builtin_fmaf(z[kb].v[rg2 * 4 + 1], L2E, -mL));
        float pp2 = exp2f(__builtin_fmaf(z[kb].v[rg2 * 4 + 2], L2E, -mL));
        float pp3 = exp2f(__builtin_fmaf(z[kb].v[rg2 * 4 + 3], L2E, -mL));
        ps0 += pp0; ps1 += pp1; ps2 += pp2; ps3 += pp3;
        u[kb][rg2][0] = cvtpk(pp0, pp1);
        u[kb][rg2][1] = cvtpk(pp2, pp3);
      }
    float ps = (ps0 + ps1) + (ps2 + ps3);
    {
      v2i r = pl32swap(__float_as_int(ps), __float_as_int(ps));
      ps = __int_as_float(r.x) + __int_as_float(r.y);
    }
    lrun += ps;
    // PV: redistribute P via permlane32_swap into A-frags, mfma against Vs
    const char* vsb = (const char*)&Vs[0][0] + cur * 8192;
    __builtin_amdgcn_s_setprio(1);
#pragma unroll
    for (int km = 0; km < 4; ++km) {
      const int kb = km >> 1, j = km & 1;
      v2i s0 = pl32swap(u[kb][2 * j][0], u[kb][2 * j + 1][0]);
      v2i s1 = pl32swap(u[kb][2 * j][1], u[kb][2 * j + 1][1]);
      i4 pw = { s0.x, s1.x, s0.y, s1.y };
      frag8 pf = *(frag8*)&pw;
#pragma unroll
      for (int nd = 0; nd < 2; ++nd) {
        frag8 vf = *(const frag8*)(vsb + voff[km * 2 + nd]);
        oacc[nd] = mfma32(pf, vf, oacc[nd]);
      }
    }
    __builtin_amdgcn_s_setprio(0);
    asm volatile("s_waitcnt lgkmcnt(0)" ::: "memory");
    __builtin_amdgcn_s_barrier();               // B: all waves done with LDS reads
    if (tt + 1 < 32) STAGE_M(tt + 1);           // Ms free: restage for next tile
  }
  // epilogue: normalize + store [B,S,E] bf16
  float linv = 1.0f / lrun;
#pragma unroll
  for (int rg = 0; rg < 16; ++rg) {
    int q_r = (rg & 3) + 8 * (rg >> 2) + 4 * hh;
    float lq = __int_as_float(__builtin_amdgcn_ds_bpermute(q_r << 2, __float_as_int(linv)));
    int gq = qt * 128 + w * 32 + q_r;
    size_t rowoff = (size_t)(b * 2048 + gq) * 1024 + hd * 64;
#pragma unroll
    for (int nd = 0; nd < 2; ++nd)
      ao_out[rowoff + nd * 32 + l31] = f2bf_hw(oacc[nd][rg] * lq);
  }
}

// ---------------- out proj GEMM: [4096,1024]x[1024,1024]^T + bias -> fp32 ----------------
// BM=64 tiles -> 512 blocks (2/CU), LDS 24KB, acc[2][4] per wave.
__global__ __launch_bounds__(256) void k_gemm_out(
    const u16* __restrict__ A, const u16* __restrict__ B,
    const float* __restrict__ bias, float* __restrict__ out) {
  __shared__ __align__(16) u16 As[64 * 64];
  __shared__ __align__(16) u16 Bs[128 * 64];
  const int mbase = blockIdx.y * 64;
  const int nbase = blockIdx.x * 128;
  const int t = threadIdx.x;
  const int lane = t & 63;
  const int w = t >> 6;
  const int wm = w >> 1, wn = w & 1;
  const facc4 vzero = {0.f, 0.f, 0.f, 0.f};
  facc4 acc[2][4];
#pragma unroll
  for (int i = 0; i < 2; ++i)
#pragma unroll
    for (int j = 0; j < 4; ++j) acc[i][j] = vzero;

  for (int kt = 0; kt < 16; ++kt) {
    __syncthreads();
#pragma unroll
    for (int i = 0; i < 2; ++i) {
      int c = i * 256 + t;
      int row = c >> 3, cs = c & 7;
      int scs = cs ^ (row & 7);
      gload16(A + (size_t)(mbase + row) * 1024 + kt * 64 + scs * 8,
              As + (size_t)(i * 256 + w * 64) * 8);
    }
#pragma unroll
    for (int i = 0; i < 4; ++i) {
      int c = i * 256 + t;
      int row = c >> 3, cs = c & 7;
      int scs = cs ^ (row & 7);
      gload16(B + (size_t)(nbase + row) * 1024 + kt * 64 + scs * 8,
              Bs + (size_t)(i * 256 + w * 64) * 8);
    }
    __syncthreads();
#pragma unroll
    for (int ks = 0; ks < 2; ++ks) {
      frag8 af[2], bfr[4];
#pragma unroll
      for (int mi = 0; mi < 2; ++mi) {
        int row = wm * 32 + mi * 16 + (lane & 15);
        int off = (ks * 64 + ((lane >> 4) << 4)) ^ ((row & 7) << 4);
        af[mi] = *(const frag8*)((const char*)As + row * 128 + off);
      }
#pragma unroll
      for (int ni = 0; ni < 4; ++ni) {
        int row = wn * 64 + ni * 16 + (lane & 15);
        int off = (ks * 64 + ((lane >> 4) << 4)) ^ ((row & 7) << 4);
        bfr[ni] = *(const frag8*)((const char*)Bs + row * 128 + off);
      }
#pragma unroll
      for (int mi = 0; mi < 2; ++mi)
#pragma unroll
        for (int ni = 0; ni < 4; ++ni)
          acc[mi][ni] = mfma16(af[mi], bfr[ni], acc[mi][ni]);
    }
  }
  const int r0 = (lane >> 4) << 2;
#pragma unroll
  for (int ni = 0; ni < 4; ++ni) {
    const int gc = nbase + wn * 64 + ni * 16 + (lane & 15);
    const float bi = bias[gc];
#pragma unroll
    for (int mi = 0; mi < 2; ++mi)
#pragma unroll
      for (int r = 0; r < 4; ++r) {
        const int gr = mbase + wm * 32 + mi * 16 + r0 + r;
        out[(size_t)gr * 1024 + gc] = acc[mi][ni][r] + bi;
      }
  }
}

extern "C" void kernel_launch(void* const* d_in, const int* in_sizes, int n_in,
                              void* d_out, int out_size, void* d_ws, size_t ws_size,
                              hipStream_t stream) {
  const float* x    = (const float*)d_in[0];
  const float* mask = (const float*)d_in[1];
  const float* wi   = (const float*)d_in[2];
  const float* bi   = (const float*)d_in[3];
  const float* wo   = (const float*)d_in[4];
  const float* bo   = (const float*)d_in[5];
  const float* la   = (const float*)d_in[6];
  const float* lb   = (const float*)d_in[7];
  float* out = (float*)d_out;

  char* ws = (char*)d_ws;
  u16* x_bf  = (u16*)ws;              ws += (size_t)4096 * 1024 * 2;
  u16* w_bf  = (u16*)ws;              ws += (size_t)3072 * 1024 * 2;
  u16* wo_bf = (u16*)ws;              ws += (size_t)1024 * 1024 * 2;
  u16* q_ws  = (u16*)ws;              ws += (size_t)4096 * 1024 * 2;
  u16* k_ws  = (u16*)ws;              ws += (size_t)4096 * 1024 * 2;
  u16* v_t   = (u16*)ws;              ws += (size_t)4096 * 1024 * 2;
  u16* a_ws  = (u16*)ws;              ws += (size_t)4096 * 1024 * 2;
  u16* m_bf  = (u16*)ws;              ws += (size_t)4096 * 2048 * 2;
  float* xa  = (float*)ws;            ws += (size_t)4096 * 8 * 4;

  k_prep<<<dim3(7168), dim3(256), 0, stream>>>(wi, w_bf, wo, wo_bf,
                                               x, la, xa, x_bf, mask, m_bf);
  k_gemm_qkv<<<dim3(24, 32), dim3(256), 0, stream>>>(x_bf, w_bf, bi, xa, lb,
                                                     q_ws, k_ws, v_t);
  k_attn<<<dim3(512), dim3(256), 0, stream>>>(q_ws, k_ws, v_t, m_bf, a_ws);
  k_gemm_out<<<dim3(8, 64), dim3(256), 0, stream>>>(a_ws, wo_bf, bo, out);
}

// Round 19
// 139.576 us; speedup vs baseline: 1.1161x; 1.0898x over previous
//
#include <hip/hip_runtime.h>
#include <hip/hip_bf16.h>
#include <math.h>

typedef unsigned short u16;
typedef unsigned int u32;
typedef __attribute__((ext_vector_type(8))) short frag8;   // 8 x bf16 (4 VGPR)
typedef __attribute__((ext_vector_type(4))) short short4v; // 4 x bf16
typedef __attribute__((ext_vector_type(4))) float facc4;   // 16x16 MFMA accumulator
typedef __attribute__((ext_vector_type(16))) float facc16; // 32x32 MFMA accumulator
typedef __attribute__((ext_vector_type(2))) int v2i;
typedef __attribute__((ext_vector_type(4))) int i4;

typedef __attribute__((address_space(3))) void lds_void;
typedef const __attribute__((address_space(1))) void gbl_void;

__device__ __forceinline__ void gload16(const void* g, void* l) {
  __builtin_amdgcn_global_load_lds((gbl_void*)g, (lds_void*)l, 16, 0, 0);
}

__device__ __forceinline__ u16 f2bf(float f) {
  union { float f; unsigned u; } v; v.f = f;
  unsigned r = v.u + 0x7FFFu + ((v.u >> 16) & 1u);   // RNE
  return (u16)(r >> 16);
}

__device__ __forceinline__ u16 f2bf_hw(float f) {
  __hip_bfloat16 h = __float2bfloat16(f);
  return *(u16*)&h;
}

__device__ __forceinline__ facc4 mfma16(frag8 a, frag8 b, facc4 c) {
  return __builtin_amdgcn_mfma_f32_16x16x32_bf16(a, b, c, 0, 0, 0);
}
__device__ __forceinline__ facc16 mfma32(frag8 a, frag8 b, facc16 c) {
  return __builtin_amdgcn_mfma_f32_32x32x16_bf16(a, b, c, 0, 0, 0);
}
__device__ __forceinline__ v2i pl32swap(int x, int y) {
  return __builtin_amdgcn_permlane32_swap(x, y, false, false);
}
__device__ __forceinline__ float vmax3(float a, float b, float c) {
  float d;
  asm("v_max3_f32 %0, %1, %2, %3" : "=v"(d) : "v"(a), "v"(b), "v"(c));
  return d;
}
__device__ __forceinline__ u32 cvtpk(float lo, float hi) {   // lo->bits[15:0], hi->bits[31:16]
  u32 r;
  asm("v_cvt_pk_bf16_f32 %0, %1, %2" : "=v"(r) : "v"(lo), "v"(hi));
  return r;
}
// raw v_exp_f32 (2^x): 1 trans-pipe inst; args bounded <= ~11.5, large-negative
// flush to 0 which is exactly correct for softmax p-values.
__device__ __forceinline__ float fexp2(float x) {
  return __builtin_amdgcn_exp2f(x);
}

// ---------------- fused prep: weights cvt + LoRA xa + x cvt + mask cvt/swizzle ----
// blocks [0,1536): wi->bf16; [1536,2048): wo->bf16; [2048,3072): k_xa;
// [3072,7168): mask fp32 -> bf16 pre-swizzled rows.
__global__ __launch_bounds__(256) void k_prep(
    const float* __restrict__ wi, u16* __restrict__ w_bf,
    const float* __restrict__ wo, u16* __restrict__ wo_bf,
    const float* __restrict__ x, const float* __restrict__ la,
    float* __restrict__ xa, u16* __restrict__ xb,
    const float* __restrict__ m, u16* __restrict__ mb) {
  const int blk = blockIdx.x;
  if (blk < 2048) {
    const float* in; u16* out; int i;
    if (blk < 1536) { in = wi; out = w_bf; i = (blk * 256 + threadIdx.x) * 8; }
    else { in = wo; out = wo_bf; i = ((blk - 1536) * 256 + threadIdx.x) * 8; }
    float4 a = *(const float4*)(in + i);
    float4 b = *(const float4*)(in + i + 4);
    frag8 o;
    o[0] = (short)f2bf(a.x); o[1] = (short)f2bf(a.y);
    o[2] = (short)f2bf(a.z); o[3] = (short)f2bf(a.w);
    o[4] = (short)f2bf(b.x); o[5] = (short)f2bf(b.y);
    o[6] = (short)f2bf(b.z); o[7] = (short)f2bf(b.w);
    *(frag8*)(out + i) = o;
  } else if (blk < 3072) {
    const int row = (blk - 2048) * 4 + (threadIdx.x >> 6);
    const int lane = threadIdx.x & 63;
    const float* xr = x + (size_t)row * 1024;
    float s[8];
#pragma unroll
    for (int j = 0; j < 8; ++j) s[j] = 0.f;
    for (int c = lane * 4; c < 1024; c += 256) {
      float4 xv = *(const float4*)(xr + c);
      short4v o;
      o[0] = (short)f2bf(xv.x); o[1] = (short)f2bf(xv.y);
      o[2] = (short)f2bf(xv.z); o[3] = (short)f2bf(xv.w);
      *(short4v*)(xb + (size_t)row * 1024 + c) = o;
#pragma unroll
      for (int j = 0; j < 8; ++j) {
        float4 av = *(const float4*)(la + j * 1024 + c);
        s[j] += xv.x * av.x + xv.y * av.y + xv.z * av.z + xv.w * av.w;
      }
    }
#pragma unroll
    for (int j = 0; j < 8; ++j) {
#pragma unroll
      for (int m_ = 1; m_ < 64; m_ <<= 1) s[j] += __shfl_xor(s[j], m_);
    }
    if (lane == 0) {
#pragma unroll
      for (int j = 0; j < 8; ++j) xa[(size_t)row * 8 + j] = s[j];
    }
  } else {
    const int row = blk - 3072;           // b*2048 + q
    const int q = row & 2047;
    const int t = threadIdx.x;
    const int T = t >> 3, c = t & 7;
    const float* src = m + (size_t)row * 2048 + T * 64 + c * 8;
    float4 a = *(const float4*)src;
    float4 b = *(const float4*)(src + 4);
    u32 g0a = cvtpk(a.x, a.y), g0b = cvtpk(a.z, a.w);
    u32 g1a = cvtpk(b.x, b.y), g1b = cvtpk(b.z, b.w);
    i4 o;
    if (q & 1) { o[0] = (int)g1a; o[1] = (int)g1b; o[2] = (int)g0a; o[3] = (int)g0b; }
    else       { o[0] = (int)g0a; o[1] = (int)g0b; o[2] = (int)g1a; o[3] = (int)g1b; }
    const int cp = c ^ ((q & 15) >> 1);
    *(i4*)(mb + (size_t)row * 2048 + T * 64 + cp * 8) = o;
  }
}

// ---------------- QKV GEMM: [4096,1024]x[3072,1024]^T + bias + LoRA ----------------
// q,k written [B,H,S,D]; V written TRANSPOSED [B,H,D,S] via LDS-transposed
// coalesced epilogue (k_vt fused away; As/Bs aliased as the transpose tile).
__global__ __launch_bounds__(256) void k_gemm_qkv(
    const u16* __restrict__ A, const u16* __restrict__ B,
    const float* __restrict__ bias, const float* __restrict__ xa,
    const float* __restrict__ lb,
    u16* __restrict__ qw, u16* __restrict__ kw, u16* __restrict__ vw) {
  __shared__ __align__(16) u16 smem[2 * 128 * 64];   // As | Bs, reused as T[128][128]
  u16* As = smem;
  u16* Bs = smem + 128 * 64;
  const int mbase = blockIdx.y * 128;
  const int nbase = blockIdx.x * 128;
  const int t = threadIdx.x;
  const int lane = t & 63;
  const int w = t >> 6;
  const int wm = w >> 1, wn = w & 1;
  const facc4 vzero = {0.f, 0.f, 0.f, 0.f};
  facc4 acc[4][4];
#pragma unroll
  for (int i = 0; i < 4; ++i)
#pragma unroll
    for (int j = 0; j < 4; ++j) acc[i][j] = vzero;

  for (int kt = 0; kt < 16; ++kt) {
    __syncthreads();
#pragma unroll
    for (int i = 0; i < 4; ++i) {
      int c = i * 256 + t;
      int row = c >> 3, cs = c & 7;
      int scs = cs ^ (row & 7);                 // pre-swizzled global source
      gload16(A + (size_t)(mbase + row) * 1024 + kt * 64 + scs * 8,
              As + (size_t)(i * 256 + w * 64) * 8);
      gload16(B + (size_t)(nbase + row) * 1024 + kt * 64 + scs * 8,
              Bs + (size_t)(i * 256 + w * 64) * 8);
    }
    __syncthreads();
#pragma unroll
    for (int ks = 0; ks < 2; ++ks) {
      frag8 af[4], bfr[4];
#pragma unroll
      for (int mi = 0; mi < 4; ++mi) {
        int row = wm * 64 + mi * 16 + (lane & 15);
        int off = (ks * 64 + ((lane >> 4) << 4)) ^ ((row & 7) << 4);
        af[mi] = *(const frag8*)((const char*)As + row * 128 + off);
      }
#pragma unroll
      for (int ni = 0; ni < 4; ++ni) {
        int row = wn * 64 + ni * 16 + (lane & 15);
        int off = (ks * 64 + ((lane >> 4) << 4)) ^ ((row & 7) << 4);
        bfr[ni] = *(const frag8*)((const char*)Bs + row * 128 + off);
      }
#pragma unroll
      for (int mi = 0; mi < 4; ++mi)
#pragma unroll
        for (int ni = 0; ni < 4; ++ni)
          acc[mi][ni] = mfma16(af[mi], bfr[ni], acc[mi][ni]);
    }
  }
  // epilogue: bias + LoRA(fp32) + split/scale
  const int which = nbase >> 10;
  const int r0 = (lane >> 4) << 2;
  float bi_[4]; float4 lb0_[4], lb1_[4]; int hh[4], dd[4];
#pragma unroll
  for (int ni = 0; ni < 4; ++ni) {
    const int gc = nbase + wn * 64 + ni * 16 + (lane & 15);
    bi_[ni] = bias[gc];
    lb0_[ni] = *(const float4*)(lb + (size_t)gc * 8);
    lb1_[ni] = *(const float4*)(lb + (size_t)gc * 8 + 4);
    const int e = gc & 1023;
    hh[ni] = e >> 6; dd[ni] = e & 63;
  }
  if (which != 2) {
    // Q/K: direct [B,H,S,D] scatter (d consecutive across 16 lanes -> 32B runs)
#pragma unroll
    for (int mi = 0; mi < 4; ++mi) {
#pragma unroll
      for (int r = 0; r < 4; ++r) {
        const int gr = mbase + wm * 64 + mi * 16 + r0 + r;
        const float4 xa0 = *(const float4*)(xa + (size_t)gr * 8);
        const float4 xa1 = *(const float4*)(xa + (size_t)gr * 8 + 4);
        const int bb = gr >> 11, s = gr & 2047;
        const size_t rbase = ((size_t)(bb * 16) * 2048 + (size_t)s) * 64;
#pragma unroll
        for (int ni = 0; ni < 4; ++ni) {
          float v = acc[mi][ni][r] + bi_[ni]
                  + xa0.x * lb0_[ni].x + xa0.y * lb0_[ni].y + xa0.z * lb0_[ni].z + xa0.w * lb0_[ni].w
                  + xa1.x * lb1_[ni].x + xa1.y * lb1_[ni].y + xa1.z * lb1_[ni].z + xa1.w * lb1_[ni].w;
          const size_t idx = rbase + (size_t)hh[ni] * (2048 * 64) + dd[ni];
          if (which == 0) qw[idx] = f2bf(v * 0.125f);
          else            kw[idx] = f2bf(v);
        }
      }
    }
  } else {
    // V: transpose in LDS (T[e][s], XOR-swizzled rows), then coalesced [B,H,D,S] store
    __syncthreads();          // all waves done reading As/Bs
#pragma unroll
    for (int mi = 0; mi < 4; ++mi) {
#pragma unroll
      for (int r = 0; r < 4; ++r) {
        const int rowl = wm * 64 + mi * 16 + r0 + r;   // s-local 0..127
        const int gr = mbase + rowl;
        const float4 xa0 = *(const float4*)(xa + (size_t)gr * 8);
        const float4 xa1 = *(const float4*)(xa + (size_t)gr * 8 + 4);
#pragma unroll
        for (int ni = 0; ni < 4; ++ni) {
          float v = acc[mi][ni][r] + bi_[ni]
                  + xa0.x * lb0_[ni].x + xa0.y * lb0_[ni].y + xa0.z * lb0_[ni].z + xa0.w * lb0_[ni].w
                  + xa1.x * lb1_[ni].x + xa1.y * lb1_[ni].y + xa1.z * lb1_[ni].z + xa1.w * lb1_[ni].w;
          const int col = wn * 64 + ni * 16 + (lane & 15);   // e-local 0..127
          smem[col * 128 + (rowl ^ ((col & 15) << 3))] = f2bf(v);
        }
      }
    }
    __syncthreads();
    // store: wave w covers cols [32w,32w+32); per iter 4 cols x 16 s-chunks of 8
    const int bb = mbase >> 11, s0 = mbase & 2047;
    const int ebase = nbase - 2048;
#pragma unroll
    for (int it = 0; it < 8; ++it) {
      const int col = w * 32 + it * 4 + (lane >> 4);
      const int chunk = lane & 15;
      const int prow = (chunk * 8) ^ ((col & 15) << 3);
      frag8 val = *(const frag8*)(smem + col * 128 + prow);
      const int e = ebase + col, h = e >> 6, d = e & 63;
      *(frag8*)(vw + ((size_t)(bb * 16 + h) * 64 + d) * 2048 + s0 + chunk * 8) = val;
    }
  }
}

// ---------------- flash attention (swapped QK^T, in-register softmax) ----------------
// q,k: [B,H,S,D] bf16 (q pre-scaled); vt: [B,H,D,S] bf16; mb: bf16 swizzled mask
// out: [B,S,H*D] bf16. 4 waves x 32 q-rows; KVBLK 64; 32x32x16 MFMA.
// Grid: 1-D 512, XCD-partitioned (each head's K/V L2-resident in one XCD).
// Ms SINGLE-buffered -> LDS 48KB; launch_bounds(256,3); raw v_exp_f32 softmax.
__global__ __launch_bounds__(256, 3) void k_attn(
    const u16* __restrict__ qw, const u16* __restrict__ kw,
    const u16* __restrict__ vt, const u16* __restrict__ mb,
    u16* __restrict__ ao_out) {
  __shared__ __align__(16) u16 Ks[2][64 * 64];    // [kv][d] rows 128B, XOR-swizzled
  __shared__ __align__(16) u16 Vs[2][64 * 64];    // [d][kv] rows 128B, XOR-swizzled
  __shared__ __align__(16) u16 Ms[128 * 64];      // [q][kv] bf16, granule-swizzled
  const int id = blockIdx.x;
  const int xcd = id & 7;
  const int r_ = id >> 3;
  const int qt = r_ & 15;
  const int bh = xcd * 4 + (r_ >> 4);             // 4 heads per XCD, same b per XCD
  const int b = bh >> 4, hd = bh & 15;
  const int t = threadIdx.x, lane = t & 63, w = t >> 6;
  const int l31 = lane & 31, hh = lane >> 5;
  const int q = qt * 128 + w * 32 + l31;
  const size_t hoff = (size_t)bh * (2048 * 64);
  const float L2E = 1.44269504088896341f;

  frag8 qf[4];
  {
    const u16* qp = qw + hoff + (size_t)q * 64 + hh * 8;
#pragma unroll
    for (int dk = 0; dk < 4; ++dk) qf[dk] = *(const frag8*)(qp + dk * 16);
  }
  const u16* mrowb = mb + (size_t)(b * 2048 + qt * 128) * 2048;   // block mask base

  // hoisted LDS byte offsets (loop-invariant)
  int koff[8], voff[8], moff[8];
#pragma unroll
  for (int kb = 0; kb < 2; ++kb) {
    int row = kb * 32 + l31, sw = (row & 7) << 4;
#pragma unroll
    for (int dk = 0; dk < 4; ++dk)
      koff[kb * 4 + dk] = row * 128 + ((dk * 32 + hh * 16) ^ sw);
  }
#pragma unroll
  for (int km = 0; km < 4; ++km)
#pragma unroll
    for (int nd = 0; nd < 2; ++nd) {
      int row = nd * 32 + l31, sw = (row & 7) << 4;
      voff[km * 2 + nd] = row * 128 + ((km * 32 + hh * 16) ^ sw);
    }
  {
    int rowq = w * 32 + l31, msw = rowq & 15;
#pragma unroll
    for (int kb = 0; kb < 2; ++kb)
#pragma unroll
      for (int rg2 = 0; rg2 < 4; ++rg2)
        moff[kb * 4 + rg2] = rowq * 128 + ((((kb * 4 + rg2) * 2 + hh) ^ msw) * 8);
  }

  float mrun = -__builtin_inff(), lrun = 0.f;
  facc16 oacc[2];
#pragma unroll
  for (int nd = 0; nd < 2; ++nd)
#pragma unroll
    for (int rg = 0; rg < 16; ++rg) oacc[nd][rg] = 0.f;

  // stage K/V tile: 2 K + 2 V = 4 gload16 per thread
  auto STAGE_KV = [&](int buf, int tile) {
    const int kv0 = tile * 64;
#pragma unroll
    for (int i = 0; i < 2; ++i) {
      int c = i * 256 + t;
      int r = c >> 3, cc = c & 7;
      int sc = cc ^ (r & 7);
      gload16(kw + hoff + (size_t)(kv0 + r) * 64 + sc * 8, (char*)&Ks[buf][0] + c * 16);
      gload16(vt + hoff + (size_t)r * 2048 + kv0 + sc * 8, (char*)&Vs[buf][0] + c * 16);
    }
  };
  // stage mask tile into the single Ms buffer: 4 gload16 per thread
  auto STAGE_M = [&](int tile) {
    const int kv0 = tile * 64;
#pragma unroll
    for (int i = 0; i < 4; ++i) {
      int c = i * 256 + t;
      int row = c >> 3, ch = c & 7;
      gload16(mrowb + (size_t)row * 2048 + kv0 + ch * 8, (char*)&Ms[0] + c * 16);
    }
  };

  STAGE_KV(0, 0);
  STAGE_M(0);

  typedef union { facc16 v; float4 f[4]; } ZU;

  for (int tt = 0; tt < 32; ++tt) {
    const int cur = tt & 1;
    if (tt + 1 < 32) {
      STAGE_KV(cur ^ 1, tt + 1);                 // 4 loads in flight past the wait
      asm volatile("s_waitcnt vmcnt(4)" ::: "memory");   // KV(tt)+M(tt) landed
    } else {
      asm volatile("s_waitcnt vmcnt(0)" ::: "memory");
    }
    __builtin_amdgcn_s_barrier();                // A: Ks/Vs[cur] + Ms(tt) visible

    // mask from LDS -> C-in (bf16 unpack by shift/mask)
    const char* msb = (const char*)&Ms[0];
    ZU z[2];
#pragma unroll
    for (int kb = 0; kb < 2; ++kb)
#pragma unroll
      for (int rg2 = 0; rg2 < 4; ++rg2) {
        v2i m2 = *(const v2i*)(msb + moff[kb * 4 + rg2]);
        z[kb].v[rg2 * 4 + 0] = __int_as_float(m2.x << 16);
        z[kb].v[rg2 * 4 + 1] = __int_as_float(m2.x & 0xFFFF0000);
        z[kb].v[rg2 * 4 + 2] = __int_as_float(m2.y << 16);
        z[kb].v[rg2 * 4 + 3] = __int_as_float(m2.y & 0xFFFF0000);
      }

    // S^T = K Q^T + mask : lane holds S[k][q] for its q = l31
    const char* ksb = (const char*)&Ks[0][0] + cur * 8192;
    __builtin_amdgcn_s_setprio(1);
#pragma unroll
    for (int kb = 0; kb < 2; ++kb)
#pragma unroll
      for (int dk = 0; dk < 4; ++dk) {
        frag8 kf = *(const frag8*)(ksb + koff[kb * 4 + dk]);
        z[kb].v = mfma32(kf, qf[dk], z[kb].v);
      }
    __builtin_amdgcn_s_setprio(0);

    // row max: max3 tree over 32 values, then one permlane32_swap
    float tm;
    {
      const facc16& a = z[0].v; const facc16& c = z[1].v;
      float g0 = vmax3(a[0], a[1], a[2]);
      float g1 = vmax3(a[3], a[4], a[5]);
      float g2 = vmax3(a[6], a[7], a[8]);
      float g3 = vmax3(a[9], a[10], a[11]);
      float g4 = vmax3(a[12], a[13], a[14]);
      float g5 = vmax3(a[15], c[0], c[1]);
      float g6 = vmax3(c[2], c[3], c[4]);
      float g7 = vmax3(c[5], c[6], c[7]);
      float g8 = vmax3(c[8], c[9], c[10]);
      float g9 = vmax3(c[11], c[12], c[13]);
      float h0 = vmax3(g0, g1, g2);
      float h1 = vmax3(g3, g4, g5);
      float h2 = vmax3(g6, g7, g8);
      float h3 = vmax3(g9, c[14], c[15]);
      float t0 = vmax3(h0, h1, h2);
      tm = fmaxf(t0, h3);
      v2i r = pl32swap(__float_as_int(tm), __float_as_int(tm));
      tm = fmaxf(__int_as_float(r.x), __int_as_float(r.y));
    }
    // deferred rescale (cold path)
    if (__any(tm > mrun + 8.f)) {
      float nm = fmaxf(mrun, tm);
      float sc = fexp2((mrun - nm) * L2E);
      mrun = nm; lrun *= sc;
#pragma unroll
      for (int rg = 0; rg < 16; ++rg) {
        int q_r = (rg & 3) + 8 * (rg >> 2) + 4 * hh;
        float scq = __int_as_float(__builtin_amdgcn_ds_bpermute(q_r << 2, __float_as_int(sc)));
        oacc[0][rg] *= scq; oacc[1][rg] *= scq;
      }
    }
    // exp + row-sum + pack (raw v_exp_f32 + cvt_pk)
    const float mL = mrun * L2E;
    float ps0 = 0.f, ps1 = 0.f, ps2 = 0.f, ps3 = 0.f;
    u32 u[2][4][2];
#pragma unroll
    for (int kb = 0; kb < 2; ++kb)
#pragma unroll
      for (int rg2 = 0; rg2 < 4; ++rg2) {
        float pp0 = fexp2(__builtin_fmaf(z[kb].v[rg2 * 4 + 0], L2E, -mL));
        float pp1 = fexp2(__builtin_fmaf(z[kb].v[rg2 * 4 + 1], L2E, -mL));
        float pp2 = fexp2(__builtin_fmaf(z[kb].v[rg2 * 4 + 2], L2E, -mL));
        float pp3 = fexp2(__builtin_fmaf(z[kb].v[rg2 * 4 + 3], L2E, -mL));
        ps0 += pp0; ps1 += pp1; ps2 += pp2; ps3 += pp3;
        u[kb][rg2][0] = cvtpk(pp0, pp1);
        u[kb][rg2][1] = cvtpk(pp2, pp3);
      }
    float ps = (ps0 + ps1) + (ps2 + ps3);
    {
      v2i r = pl32swap(__float_as_int(ps), __float_as_int(ps));
      ps = __int_as_float(r.x) + __int_as_float(r.y);
    }
    lrun += ps;
    // PV: redistribute P via permlane32_swap into A-frags, mfma against Vs
    const char* vsb = (const char*)&Vs[0][0] + cur * 8192;
    __builtin_amdgcn_s_setprio(1);
#pragma unroll
    for (int km = 0; km < 4; ++km) {
      const int kb = km >> 1, j = km & 1;
      v2i s0 = pl32swap(u[kb][2 * j][0], u[kb][2 * j + 1][0]);
      v2i s1 = pl32swap(u[kb][2 * j][1], u[kb][2 * j + 1][1]);
      i4 pw = { s0.x, s1.x, s0.y, s1.y };
      frag8 pf = *(frag8*)&pw;
#pragma unroll
      for (int nd = 0; nd < 2; ++nd) {
        frag8 vf = *(const frag8*)(vsb + voff[km * 2 + nd]);
        oacc[nd] = mfma32(pf, vf, oacc[nd]);
      }
    }
    __builtin_amdgcn_s_setprio(0);
    asm volatile("s_waitcnt lgkmcnt(0)" ::: "memory");
    __builtin_amdgcn_s_barrier();               // B: all waves done with LDS reads
    if (tt + 1 < 32) STAGE_M(tt + 1);           // Ms free: restage for next tile
  }
  // epilogue: normalize + store [B,S,E] bf16
  float linv = 1.0f / lrun;
#pragma unroll
  for (int rg = 0; rg < 16; ++rg) {
    int q_r = (rg & 3) + 8 * (rg >> 2) + 4 * hh;
    float lq = __int_as_float(__builtin_amdgcn_ds_bpermute(q_r << 2, __float_as_int(linv)));
    int gq = qt * 128 + w * 32 + q_r;
    size_t rowoff = (size_t)(b * 2048 + gq) * 1024 + hd * 64;
#pragma unroll
    for (int nd = 0; nd < 2; ++nd)
      ao_out[rowoff + nd * 32 + l31] = f2bf_hw(oacc[nd][rg] * lq);
  }
}

// ---------------- out proj GEMM: [4096,1024]x[1024,1024]^T + bias -> fp32 ----------------
// BM=64 tiles -> 512 blocks (2/CU), LDS 24KB, acc[2][4] per wave.
__global__ __launch_bounds__(256) void k_gemm_out(
    const u16* __restrict__ A, const u16* __restrict__ B,
    const float* __restrict__ bias, float* __restrict__ out) {
  __shared__ __align__(16) u16 As[64 * 64];
  __shared__ __align__(16) u16 Bs[128 * 64];
  const int mbase = blockIdx.y * 64;
  const int nbase = blockIdx.x * 128;
  const int t = threadIdx.x;
  const int lane = t & 63;
  const int w = t >> 6;
  const int wm = w >> 1, wn = w & 1;
  const facc4 vzero = {0.f, 0.f, 0.f, 0.f};
  facc4 acc[2][4];
#pragma unroll
  for (int i = 0; i < 2; ++i)
#pragma unroll
    for (int j = 0; j < 4; ++j) acc[i][j] = vzero;

  for (int kt = 0; kt < 16; ++kt) {
    __syncthreads();
#pragma unroll
    for (int i = 0; i < 2; ++i) {
      int c = i * 256 + t;
      int row = c >> 3, cs = c & 7;
      int scs = cs ^ (row & 7);
      gload16(A + (size_t)(mbase + row) * 1024 + kt * 64 + scs * 8,
              As + (size_t)(i * 256 + w * 64) * 8);
    }
#pragma unroll
    for (int i = 0; i < 4; ++i) {
      int c = i * 256 + t;
      int row = c >> 3, cs = c & 7;
      int scs = cs ^ (row & 7);
      gload16(B + (size_t)(nbase + row) * 1024 + kt * 64 + scs * 8,
              Bs + (size_t)(i * 256 + w * 64) * 8);
    }
    __syncthreads();
#pragma unroll
    for (int ks = 0; ks < 2; ++ks) {
      frag8 af[2], bfr[4];
#pragma unroll
      for (int mi = 0; mi < 2; ++mi) {
        int row = wm * 32 + mi * 16 + (lane & 15);
        int off = (ks * 64 + ((lane >> 4) << 4)) ^ ((row & 7) << 4);
        af[mi] = *(const frag8*)((const char*)As + row * 128 + off);
      }
#pragma unroll
      for (int ni = 0; ni < 4; ++ni) {
        int row = wn * 64 + ni * 16 + (lane & 15);
        int off = (ks * 64 + ((lane >> 4) << 4)) ^ ((row & 7) << 4);
        bfr[ni] = *(const frag8*)((const char*)Bs + row * 128 + off);
      }
#pragma unroll
      for (int mi = 0; mi < 2; ++mi)
#pragma unroll
        for (int ni = 0; ni < 4; ++ni)
          acc[mi][ni] = mfma16(af[mi], bfr[ni], acc[mi][ni]);
    }
  }
  const int r0 = (lane >> 4) << 2;
#pragma unroll
  for (int ni = 0; ni < 4; ++ni) {
    const int gc = nbase + wn * 64 + ni * 16 + (lane & 15);
    const float bi = bias[gc];
#pragma unroll
    for (int mi = 0; mi < 2; ++mi)
#pragma unroll
      for (int r = 0; r < 4; ++r) {
        const int gr = mbase + wm * 32 + mi * 16 + r0 + r;
        out[(size_t)gr * 1024 + gc] = acc[mi][ni][r] + bi;
      }
  }
}

extern "C" void kernel_launch(void* const* d_in, const int* in_sizes, int n_in,
                              void* d_out, int out_size, void* d_ws, size_t ws_size,
                              hipStream_t stream) {
  const float* x    = (const float*)d_in[0];
  const float* mask = (const float*)d_in[1];
  const float* wi   = (const float*)d_in[2];
  const float* bi   = (const float*)d_in[3];
  const float* wo   = (const float*)d_in[4];
  const float* bo   = (const float*)d_in[5];
  const float* la   = (const float*)d_in[6];
  const float* lb   = (const float*)d_in[7];
  float* out = (float*)d_out;

  char* ws = (char*)d_ws;
  u16* x_bf  = (u16*)ws;              ws += (size_t)4096 * 1024 * 2;
  u16* w_bf  = (u16*)ws;              ws += (size_t)3072 * 1024 * 2;
  u16* wo_bf = (u16*)ws;              ws += (size_t)1024 * 1024 * 2;
  u16* q_ws  = (u16*)ws;              ws += (size_t)4096 * 1024 * 2;
  u16* k_ws  = (u16*)ws;              ws += (size_t)4096 * 1024 * 2;
  u16* v_t   = (u16*)ws;              ws += (size_t)4096 * 1024 * 2;
  u16* a_ws  = (u16*)ws;              ws += (size_t)4096 * 1024 * 2;
  u16* m_bf  = (u16*)ws;              ws += (size_t)4096 * 2048 * 2;
  float* xa  = (float*)ws;            ws += (size_t)4096 * 8 * 4;

  k_prep<<<dim3(7168), dim3(256), 0, stream>>>(wi, w_bf, wo, wo_bf,
                                               x, la, xa, x_bf, mask, m_bf);
  k_gemm_qkv<<<dim3(24, 32), dim3(256), 0, stream>>>(x_bf, w_bf, bi, xa, lb,
                                                     q_ws, k_ws, v_t);
  k_attn<<<dim3(512), dim3(256), 0, stream>>>(q_ws, k_ws, v_t, m_bf, a_ws);
  k_gemm_out<<<dim3(8, 64), dim3(256), 0, stream>>>(a_ws, wo_bf, bo, out);
}

// Round 20
// 137.346 us; speedup vs baseline: 1.1342x; 1.0162x over previous
//
#include <hip/hip_runtime.h>
#include <hip/hip_bf16.h>
#include <math.h>

typedef unsigned short u16;
typedef unsigned int u32;
typedef __attribute__((ext_vector_type(8))) short frag8;   // 8 x bf16 (4 VGPR)
typedef __attribute__((ext_vector_type(4))) short short4v; // 4 x bf16
typedef __attribute__((ext_vector_type(4))) float facc4;   // 16x16 MFMA accumulator
typedef __attribute__((ext_vector_type(16))) float facc16; // 32x32 MFMA accumulator
typedef __attribute__((ext_vector_type(2))) int v2i;
typedef __attribute__((ext_vector_type(4))) int i4;

typedef __attribute__((address_space(3))) void lds_void;
typedef const __attribute__((address_space(1))) void gbl_void;

__device__ __forceinline__ void gload16(const void* g, void* l) {
  __builtin_amdgcn_global_load_lds((gbl_void*)g, (lds_void*)l, 16, 0, 0);
}

__device__ __forceinline__ u16 f2bf(float f) {
  union { float f; unsigned u; } v; v.f = f;
  unsigned r = v.u + 0x7FFFu + ((v.u >> 16) & 1u);   // RNE
  return (u16)(r >> 16);
}

__device__ __forceinline__ facc4 mfma16(frag8 a, frag8 b, facc4 c) {
  return __builtin_amdgcn_mfma_f32_16x16x32_bf16(a, b, c, 0, 0, 0);
}
__device__ __forceinline__ facc16 mfma32(frag8 a, frag8 b, facc16 c) {
  return __builtin_amdgcn_mfma_f32_32x32x16_bf16(a, b, c, 0, 0, 0);
}
__device__ __forceinline__ v2i pl32swap(int x, int y) {
  return __builtin_amdgcn_permlane32_swap(x, y, false, false);
}
__device__ __forceinline__ float vmax3(float a, float b, float c) {
  float d;
  asm("v_max3_f32 %0, %1, %2, %3" : "=v"(d) : "v"(a), "v"(b), "v"(c));
  return d;
}
__device__ __forceinline__ u32 cvtpk(float lo, float hi) {   // lo->bits[15:0], hi->bits[31:16]
  u32 r;
  asm("v_cvt_pk_bf16_f32 %0, %1, %2" : "=v"(r) : "v"(lo), "v"(hi));
  return r;
}
// raw v_exp_f32 (2^x): 1 trans-pipe inst; args bounded <= ~11.5, large-negative
// flush to 0 which is exactly correct for softmax p-values.
__device__ __forceinline__ float fexp2(float x) {
  return __builtin_amdgcn_exp2f(x);
}

// ---------------- fused prep: weights cvt + LoRA xa + x cvt + mask cvt/swizzle ----
// blocks [0,1536): wi->bf16; [1536,2048): wo->bf16; [2048,3072): k_xa;
// [3072,7168): mask fp32 -> bf16 pre-swizzled rows.
__global__ __launch_bounds__(256) void k_prep(
    const float* __restrict__ wi, u16* __restrict__ w_bf,
    const float* __restrict__ wo, u16* __restrict__ wo_bf,
    const float* __restrict__ x, const float* __restrict__ la,
    float* __restrict__ xa, u16* __restrict__ xb,
    const float* __restrict__ m, u16* __restrict__ mb) {
  const int blk = blockIdx.x;
  if (blk < 2048) {
    const float* in; u16* out; int i;
    if (blk < 1536) { in = wi; out = w_bf; i = (blk * 256 + threadIdx.x) * 8; }
    else { in = wo; out = wo_bf; i = ((blk - 1536) * 256 + threadIdx.x) * 8; }
    float4 a = *(const float4*)(in + i);
    float4 b = *(const float4*)(in + i + 4);
    i4 o;
    o[0] = (int)cvtpk(a.x, a.y);
    o[1] = (int)cvtpk(a.z, a.w);
    o[2] = (int)cvtpk(b.x, b.y);
    o[3] = (int)cvtpk(b.z, b.w);
    *(i4*)(out + i) = o;
  } else if (blk < 3072) {
    const int row = (blk - 2048) * 4 + (threadIdx.x >> 6);
    const int lane = threadIdx.x & 63;
    const float* xr = x + (size_t)row * 1024;
    float s[8];
#pragma unroll
    for (int j = 0; j < 8; ++j) s[j] = 0.f;
    for (int c = lane * 4; c < 1024; c += 256) {
      float4 xv = *(const float4*)(xr + c);
      u32 p0 = cvtpk(xv.x, xv.y), p1 = cvtpk(xv.z, xv.w);
      v2i o; o.x = (int)p0; o.y = (int)p1;
      *(v2i*)(xb + (size_t)row * 1024 + c) = o;
#pragma unroll
      for (int j = 0; j < 8; ++j) {
        float4 av = *(const float4*)(la + j * 1024 + c);
        s[j] += xv.x * av.x + xv.y * av.y + xv.z * av.z + xv.w * av.w;
      }
    }
#pragma unroll
    for (int j = 0; j < 8; ++j) {
#pragma unroll
      for (int m_ = 1; m_ < 64; m_ <<= 1) s[j] += __shfl_xor(s[j], m_);
    }
    if (lane == 0) {
#pragma unroll
      for (int j = 0; j < 8; ++j) xa[(size_t)row * 8 + j] = s[j];
    }
  } else {
    const int row = blk - 3072;           // b*2048 + q
    const int q = row & 2047;
    const int t = threadIdx.x;
    const int T = t >> 3, c = t & 7;
    const float* src = m + (size_t)row * 2048 + T * 64 + c * 8;
    float4 a = *(const float4*)src;
    float4 b = *(const float4*)(src + 4);
    u32 g0a = cvtpk(a.x, a.y), g0b = cvtpk(a.z, a.w);
    u32 g1a = cvtpk(b.x, b.y), g1b = cvtpk(b.z, b.w);
    i4 o;
    if (q & 1) { o[0] = (int)g1a; o[1] = (int)g1b; o[2] = (int)g0a; o[3] = (int)g0b; }
    else       { o[0] = (int)g0a; o[1] = (int)g0b; o[2] = (int)g1a; o[3] = (int)g1b; }
    const int cp = c ^ ((q & 15) >> 1);
    *(i4*)(mb + (size_t)row * 2048 + T * 64 + cp * 8) = o;
  }
}

// ---------------- QKV GEMM: [4096,1024]x[3072,1024]^T + bias + LoRA ----------------
// q,k written [B,H,S,D]; V written TRANSPOSED [B,H,D,S] via LDS-transposed
// coalesced epilogue (k_vt fused away; As/Bs aliased as the transpose tile).
__global__ __launch_bounds__(256) void k_gemm_qkv(
    const u16* __restrict__ A, const u16* __restrict__ B,
    const float* __restrict__ bias, const float* __restrict__ xa,
    const float* __restrict__ lb,
    u16* __restrict__ qw, u16* __restrict__ kw, u16* __restrict__ vw) {
  __shared__ __align__(16) u16 smem[2 * 128 * 64];   // As | Bs, reused as T[128][128]
  u16* As = smem;
  u16* Bs = smem + 128 * 64;
  const int mbase = blockIdx.y * 128;
  const int nbase = blockIdx.x * 128;
  const int t = threadIdx.x;
  const int lane = t & 63;
  const int w = t >> 6;
  const int wm = w >> 1, wn = w & 1;
  const facc4 vzero = {0.f, 0.f, 0.f, 0.f};
  facc4 acc[4][4];
#pragma unroll
  for (int i = 0; i < 4; ++i)
#pragma unroll
    for (int j = 0; j < 4; ++j) acc[i][j] = vzero;

  for (int kt = 0; kt < 16; ++kt) {
    __syncthreads();
#pragma unroll
    for (int i = 0; i < 4; ++i) {
      int c = i * 256 + t;
      int row = c >> 3, cs = c & 7;
      int scs = cs ^ (row & 7);                 // pre-swizzled global source
      gload16(A + (size_t)(mbase + row) * 1024 + kt * 64 + scs * 8,
              As + (size_t)(i * 256 + w * 64) * 8);
      gload16(B + (size_t)(nbase + row) * 1024 + kt * 64 + scs * 8,
              Bs + (size_t)(i * 256 + w * 64) * 8);
    }
    __syncthreads();
#pragma unroll
    for (int ks = 0; ks < 2; ++ks) {
      frag8 af[4], bfr[4];
#pragma unroll
      for (int mi = 0; mi < 4; ++mi) {
        int row = wm * 64 + mi * 16 + (lane & 15);
        int off = (ks * 64 + ((lane >> 4) << 4)) ^ ((row & 7) << 4);
        af[mi] = *(const frag8*)((const char*)As + row * 128 + off);
      }
#pragma unroll
      for (int ni = 0; ni < 4; ++ni) {
        int row = wn * 64 + ni * 16 + (lane & 15);
        int off = (ks * 64 + ((lane >> 4) << 4)) ^ ((row & 7) << 4);
        bfr[ni] = *(const frag8*)((const char*)Bs + row * 128 + off);
      }
#pragma unroll
      for (int mi = 0; mi < 4; ++mi)
#pragma unroll
        for (int ni = 0; ni < 4; ++ni)
          acc[mi][ni] = mfma16(af[mi], bfr[ni], acc[mi][ni]);
    }
  }
  // epilogue: bias + LoRA(fp32) + split/scale
  const int which = nbase >> 10;
  const int r0 = (lane >> 4) << 2;
  float bi_[4]; float4 lb0_[4], lb1_[4]; int hh[4], dd[4];
#pragma unroll
  for (int ni = 0; ni < 4; ++ni) {
    const int gc = nbase + wn * 64 + ni * 16 + (lane & 15);
    bi_[ni] = bias[gc];
    lb0_[ni] = *(const float4*)(lb + (size_t)gc * 8);
    lb1_[ni] = *(const float4*)(lb + (size_t)gc * 8 + 4);
    const int e = gc & 1023;
    hh[ni] = e >> 6; dd[ni] = e & 63;
  }
  if (which != 2) {
    // Q/K: direct [B,H,S,D] scatter (d consecutive across 16 lanes -> 32B runs)
    const float qs = (which == 0) ? 0.125f : 1.0f;
#pragma unroll
    for (int mi = 0; mi < 4; ++mi) {
#pragma unroll
      for (int r = 0; r < 4; ++r) {
        const int gr = mbase + wm * 64 + mi * 16 + r0 + r;
        const float4 xa0 = *(const float4*)(xa + (size_t)gr * 8);
        const float4 xa1 = *(const float4*)(xa + (size_t)gr * 8 + 4);
        const int bb = gr >> 11, s = gr & 2047;
        const size_t rbase = ((size_t)(bb * 16) * 2048 + (size_t)s) * 64;
        float vv[4];
#pragma unroll
        for (int ni = 0; ni < 4; ++ni) {
          float v = acc[mi][ni][r] + bi_[ni]
                  + xa0.x * lb0_[ni].x + xa0.y * lb0_[ni].y + xa0.z * lb0_[ni].z + xa0.w * lb0_[ni].w
                  + xa1.x * lb1_[ni].x + xa1.y * lb1_[ni].y + xa1.z * lb1_[ni].z + xa1.w * lb1_[ni].w;
          vv[ni] = v * qs;
        }
        const u32 p01 = cvtpk(vv[0], vv[1]);
        const u32 p23 = cvtpk(vv[2], vv[3]);
        u16* dst = (which == 0) ? qw : kw;
        dst[rbase + (size_t)hh[0] * (2048 * 64) + dd[0]] = (u16)p01;
        dst[rbase + (size_t)hh[1] * (2048 * 64) + dd[1]] = (u16)(p01 >> 16);
        dst[rbase + (size_t)hh[2] * (2048 * 64) + dd[2]] = (u16)p23;
        dst[rbase + (size_t)hh[3] * (2048 * 64) + dd[3]] = (u16)(p23 >> 16);
      }
    }
  } else {
    // V: transpose in LDS (T[e][s], XOR-swizzled rows), then coalesced [B,H,D,S] store
    __syncthreads();          // all waves done reading As/Bs
#pragma unroll
    for (int mi = 0; mi < 4; ++mi) {
#pragma unroll
      for (int r = 0; r < 4; ++r) {
        const int rowl = wm * 64 + mi * 16 + r0 + r;   // s-local 0..127
        const int gr = mbase + rowl;
        const float4 xa0 = *(const float4*)(xa + (size_t)gr * 8);
        const float4 xa1 = *(const float4*)(xa + (size_t)gr * 8 + 4);
        float vv[4];
#pragma unroll
        for (int ni = 0; ni < 4; ++ni) {
          vv[ni] = acc[mi][ni][r] + bi_[ni]
                 + xa0.x * lb0_[ni].x + xa0.y * lb0_[ni].y + xa0.z * lb0_[ni].z + xa0.w * lb0_[ni].w
                 + xa1.x * lb1_[ni].x + xa1.y * lb1_[ni].y + xa1.z * lb1_[ni].z + xa1.w * lb1_[ni].w;
        }
        const u32 p01 = cvtpk(vv[0], vv[1]);
        const u32 p23 = cvtpk(vv[2], vv[3]);
        const int c0 = wn * 64 + 0 * 16 + (lane & 15);
        const int c1 = wn * 64 + 1 * 16 + (lane & 15);
        const int c2 = wn * 64 + 2 * 16 + (lane & 15);
        const int c3 = wn * 64 + 3 * 16 + (lane & 15);
        smem[c0 * 128 + (rowl ^ ((c0 & 15) << 3))] = (u16)p01;
        smem[c1 * 128 + (rowl ^ ((c1 & 15) << 3))] = (u16)(p01 >> 16);
        smem[c2 * 128 + (rowl ^ ((c2 & 15) << 3))] = (u16)p23;
        smem[c3 * 128 + (rowl ^ ((c3 & 15) << 3))] = (u16)(p23 >> 16);
      }
    }
    __syncthreads();
    // store: wave w covers cols [32w,32w+32); per iter 4 cols x 16 s-chunks of 8
    const int bb = mbase >> 11, s0 = mbase & 2047;
    const int ebase = nbase - 2048;
#pragma unroll
    for (int it = 0; it < 8; ++it) {
      const int col = w * 32 + it * 4 + (lane >> 4);
      const int chunk = lane & 15;
      const int prow = (chunk * 8) ^ ((col & 15) << 3);
      frag8 val = *(const frag8*)(smem + col * 128 + prow);
      const int e = ebase + col, h = e >> 6, d = e & 63;
      *(frag8*)(vw + ((size_t)(bb * 16 + h) * 64 + d) * 2048 + s0 + chunk * 8) = val;
    }
  }
}

// ---------------- flash attention (swapped QK^T, in-register softmax) ----------------
// q,k: [B,H,S,D] bf16 (q pre-scaled); vt: [B,H,D,S] bf16; mb: bf16 swizzled mask
// out: [B,S,H*D] bf16. 4 waves x 32 q-rows; KVBLK 64; 32x32x16 MFMA.
// Grid: 1-D 512, XCD-partitioned (each head's K/V L2-resident in one XCD).
// Ms SINGLE-buffered -> LDS 48KB; launch_bounds(256,3); raw v_exp_f32 softmax.
__global__ __launch_bounds__(256, 3) void k_attn(
    const u16* __restrict__ qw, const u16* __restrict__ kw,
    const u16* __restrict__ vt, const u16* __restrict__ mb,
    u16* __restrict__ ao_out) {
  __shared__ __align__(16) u16 Ks[2][64 * 64];    // [kv][d] rows 128B, XOR-swizzled
  __shared__ __align__(16) u16 Vs[2][64 * 64];    // [d][kv] rows 128B, XOR-swizzled
  __shared__ __align__(16) u16 Ms[128 * 64];      // [q][kv] bf16, granule-swizzled
  const int id = blockIdx.x;
  const int xcd = id & 7;
  const int r_ = id >> 3;
  const int qt = r_ & 15;
  const int bh = xcd * 4 + (r_ >> 4);             // 4 heads per XCD, same b per XCD
  const int b = bh >> 4, hd = bh & 15;
  const int t = threadIdx.x, lane = t & 63, w = t >> 6;
  const int l31 = lane & 31, hh = lane >> 5;
  const int q = qt * 128 + w * 32 + l31;
  const size_t hoff = (size_t)bh * (2048 * 64);
  const float L2E = 1.44269504088896341f;

  frag8 qf[4];
  {
    const u16* qp = qw + hoff + (size_t)q * 64 + hh * 8;
#pragma unroll
    for (int dk = 0; dk < 4; ++dk) qf[dk] = *(const frag8*)(qp + dk * 16);
  }
  const u16* mrowb = mb + (size_t)(b * 2048 + qt * 128) * 2048;   // block mask base

  // hoisted LDS byte offsets (loop-invariant)
  int koff[8], voff[8], moff[8];
#pragma unroll
  for (int kb = 0; kb < 2; ++kb) {
    int row = kb * 32 + l31, sw = (row & 7) << 4;
#pragma unroll
    for (int dk = 0; dk < 4; ++dk)
      koff[kb * 4 + dk] = row * 128 + ((dk * 32 + hh * 16) ^ sw);
  }
#pragma unroll
  for (int km = 0; km < 4; ++km)
#pragma unroll
    for (int nd = 0; nd < 2; ++nd) {
      int row = nd * 32 + l31, sw = (row & 7) << 4;
      voff[km * 2 + nd] = row * 128 + ((km * 32 + hh * 16) ^ sw);
    }
  {
    int rowq = w * 32 + l31, msw = rowq & 15;
#pragma unroll
    for (int kb = 0; kb < 2; ++kb)
#pragma unroll
      for (int rg2 = 0; rg2 < 4; ++rg2)
        moff[kb * 4 + rg2] = rowq * 128 + ((((kb * 4 + rg2) * 2 + hh) ^ msw) * 8);
  }

  float mrun = -__builtin_inff(), lrun = 0.f;
  facc16 oacc[2];
#pragma unroll
  for (int nd = 0; nd < 2; ++nd)
#pragma unroll
    for (int rg = 0; rg < 16; ++rg) oacc[nd][rg] = 0.f;

  // stage K/V tile: 2 K + 2 V = 4 gload16 per thread
  auto STAGE_KV = [&](int buf, int tile) {
    const int kv0 = tile * 64;
#pragma unroll
    for (int i = 0; i < 2; ++i) {
      int c = i * 256 + t;
      int r = c >> 3, cc = c & 7;
      int sc = cc ^ (r & 7);
      gload16(kw + hoff + (size_t)(kv0 + r) * 64 + sc * 8, (char*)&Ks[buf][0] + c * 16);
      gload16(vt + hoff + (size_t)r * 2048 + kv0 + sc * 8, (char*)&Vs[buf][0] + c * 16);
    }
  };
  // stage mask tile into the single Ms buffer: 4 gload16 per thread
  auto STAGE_M = [&](int tile) {
    const int kv0 = tile * 64;
#pragma unroll
    for (int i = 0; i < 4; ++i) {
      int c = i * 256 + t;
      int row = c >> 3, ch = c & 7;
      gload16(mrowb + (size_t)row * 2048 + kv0 + ch * 8, (char*)&Ms[0] + c * 16);
    }
  };

  STAGE_KV(0, 0);
  STAGE_M(0);

  typedef union { facc16 v; float4 f[4]; } ZU;

  for (int tt = 0; tt < 32; ++tt) {
    const int cur = tt & 1;
    if (tt + 1 < 32) {
      STAGE_KV(cur ^ 1, tt + 1);                 // 4 loads in flight past the wait
      asm volatile("s_waitcnt vmcnt(4)" ::: "memory");   // KV(tt)+M(tt) landed
    } else {
      asm volatile("s_waitcnt vmcnt(0)" ::: "memory");
    }
    __builtin_amdgcn_s_barrier();                // A: Ks/Vs[cur] + Ms(tt) visible

    // mask from LDS -> C-in (bf16 unpack by shift/mask)
    const char* msb = (const char*)&Ms[0];
    ZU z[2];
#pragma unroll
    for (int kb = 0; kb < 2; ++kb)
#pragma unroll
      for (int rg2 = 0; rg2 < 4; ++rg2) {
        v2i m2 = *(const v2i*)(msb + moff[kb * 4 + rg2]);
        z[kb].v[rg2 * 4 + 0] = __int_as_float(m2.x << 16);
        z[kb].v[rg2 * 4 + 1] = __int_as_float(m2.x & 0xFFFF0000);
        z[kb].v[rg2 * 4 + 2] = __int_as_float(m2.y << 16);
        z[kb].v[rg2 * 4 + 3] = __int_as_float(m2.y & 0xFFFF0000);
      }

    // S^T = K Q^T + mask : lane holds S[k][q] for its q = l31
    const char* ksb = (const char*)&Ks[0][0] + cur * 8192;
    __builtin_amdgcn_s_setprio(1);
#pragma unroll
    for (int kb = 0; kb < 2; ++kb)
#pragma unroll
      for (int dk = 0; dk < 4; ++dk) {
        frag8 kf = *(const frag8*)(ksb + koff[kb * 4 + dk]);
        z[kb].v = mfma32(kf, qf[dk], z[kb].v);
      }
    __builtin_amdgcn_s_setprio(0);

    // row max: max3 tree over 32 values, then one permlane32_swap
    float tm;
    {
      const facc16& a = z[0].v; const facc16& c = z[1].v;
      float g0 = vmax3(a[0], a[1], a[2]);
      float g1 = vmax3(a[3], a[4], a[5]);
      float g2 = vmax3(a[6], a[7], a[8]);
      float g3 = vmax3(a[9], a[10], a[11]);
      float g4 = vmax3(a[12], a[13], a[14]);
      float g5 = vmax3(a[15], c[0], c[1]);
      float g6 = vmax3(c[2], c[3], c[4]);
      float g7 = vmax3(c[5], c[6], c[7]);
      float g8 = vmax3(c[8], c[9], c[10]);
      float g9 = vmax3(c[11], c[12], c[13]);
      float h0 = vmax3(g0, g1, g2);
      float h1 = vmax3(g3, g4, g5);
      float h2 = vmax3(g6, g7, g8);
      float h3 = vmax3(g9, c[14], c[15]);
      float t0 = vmax3(h0, h1, h2);
      tm = fmaxf(t0, h3);
      v2i r = pl32swap(__float_as_int(tm), __float_as_int(tm));
      tm = fmaxf(__int_as_float(r.x), __int_as_float(r.y));
    }
    // deferred rescale (cold path)
    if (__any(tm > mrun + 8.f)) {
      float nm = fmaxf(mrun, tm);
      float sc = fexp2((mrun - nm) * L2E);
      mrun = nm; lrun *= sc;
#pragma unroll
      for (int rg = 0; rg < 16; ++rg) {
        int q_r = (rg & 3) + 8 * (rg >> 2) + 4 * hh;
        float scq = __int_as_float(__builtin_amdgcn_ds_bpermute(q_r << 2, __float_as_int(sc)));
        oacc[0][rg] *= scq; oacc[1][rg] *= scq;
      }
    }
    // exp + row-sum + pack (raw v_exp_f32 + cvt_pk)
    const float mL = mrun * L2E;
    float ps0 = 0.f, ps1 = 0.f, ps2 = 0.f, ps3 = 0.f;
    u32 u[2][4][2];
#pragma unroll
    for (int kb = 0; kb < 2; ++kb)
#pragma unroll
      for (int rg2 = 0; rg2 < 4; ++rg2) {
        float pp0 = fexp2(__builtin_fmaf(z[kb].v[rg2 * 4 + 0], L2E, -mL));
        float pp1 = fexp2(__builtin_fmaf(z[kb].v[rg2 * 4 + 1], L2E, -mL));
        float pp2 = fexp2(__builtin_fmaf(z[kb].v[rg2 * 4 + 2], L2E, -mL));
        float pp3 = fexp2(__builtin_fmaf(z[kb].v[rg2 * 4 + 3], L2E, -mL));
        ps0 += pp0; ps1 += pp1; ps2 += pp2; ps3 += pp3;
        u[kb][rg2][0] = cvtpk(pp0, pp1);
        u[kb][rg2][1] = cvtpk(pp2, pp3);
      }
    float ps = (ps0 + ps1) + (ps2 + ps3);
    {
      v2i r = pl32swap(__float_as_int(ps), __float_as_int(ps));
      ps = __int_as_float(r.x) + __int_as_float(r.y);
    }
    lrun += ps;
    // PV: redistribute P via permlane32_swap into A-frags, mfma against Vs
    const char* vsb = (const char*)&Vs[0][0] + cur * 8192;
    __builtin_amdgcn_s_setprio(1);
#pragma unroll
    for (int km = 0; km < 4; ++km) {
      const int kb = km >> 1, j = km & 1;
      v2i s0 = pl32swap(u[kb][2 * j][0], u[kb][2 * j + 1][0]);
      v2i s1 = pl32swap(u[kb][2 * j][1], u[kb][2 * j + 1][1]);
      i4 pw = { s0.x, s1.x, s0.y, s1.y };
      frag8 pf = *(frag8*)&pw;
#pragma unroll
      for (int nd = 0; nd < 2; ++nd) {
        frag8 vf = *(const frag8*)(vsb + voff[km * 2 + nd]);
        oacc[nd] = mfma32(pf, vf, oacc[nd]);
      }
    }
    __builtin_amdgcn_s_setprio(0);
    asm volatile("s_waitcnt lgkmcnt(0)" ::: "memory");
    __builtin_amdgcn_s_barrier();               // B: all waves done with LDS reads
    if (tt + 1 < 32) STAGE_M(tt + 1);           // Ms free: restage for next tile
  }
  // epilogue: normalize + store [B,S,E] bf16 (paired HW convert)
  float linv = 1.0f / lrun;
#pragma unroll
  for (int rg = 0; rg < 16; ++rg) {
    int q_r = (rg & 3) + 8 * (rg >> 2) + 4 * hh;
    float lq = __int_as_float(__builtin_amdgcn_ds_bpermute(q_r << 2, __float_as_int(linv)));
    int gq = qt * 128 + w * 32 + q_r;
    size_t rowoff = (size_t)(b * 2048 + gq) * 1024 + hd * 64;
    u32 p = cvtpk(oacc[0][rg] * lq, oacc[1][rg] * lq);
    ao_out[rowoff + l31] = (u16)p;
    ao_out[rowoff + 32 + l31] = (u16)(p >> 16);
  }
}

// ---------------- out proj GEMM: [4096,1024]x[1024,1024]^T + bias -> fp32 ----------------
// BM=64 tiles -> 512 blocks (2/CU), LDS 24KB, acc[2][4] per wave.
__global__ __launch_bounds__(256) void k_gemm_out(
    const u16* __restrict__ A, const u16* __restrict__ B,
    const float* __restrict__ bias, float* __restrict__ out) {
  __shared__ __align__(16) u16 As[64 * 64];
  __shared__ __align__(16) u16 Bs[128 * 64];
  const int mbase = blockIdx.y * 64;
  const int nbase = blockIdx.x * 128;
  const int t = threadIdx.x;
  const int lane = t & 63;
  const int w = t >> 6;
  const int wm = w >> 1, wn = w & 1;
  const facc4 vzero = {0.f, 0.f, 0.f, 0.f};
  facc4 acc[2][4];
#pragma unroll
  for (int i = 0; i < 2; ++i)
#pragma unroll
    for (int j = 0; j < 4; ++j) acc[i][j] = vzero;

  for (int kt = 0; kt < 16; ++kt) {
    __syncthreads();
#pragma unroll
    for (int i = 0; i < 2; ++i) {
      int c = i * 256 + t;
      int row = c >> 3, cs = c & 7;
      int scs = cs ^ (row & 7);
      gload16(A + (size_t)(mbase + row) * 1024 + kt * 64 + scs * 8,
              As + (size_t)(i * 256 + w * 64) * 8);
    }
#pragma unroll
    for (int i = 0; i < 4; ++i) {
      int c = i * 256 + t;
      int row = c >> 3, cs = c & 7;
      int scs = cs ^ (row & 7);
      gload16(B + (size_t)(nbase + row) * 1024 + kt * 64 + scs * 8,
              Bs + (size_t)(i * 256 + w * 64) * 8);
    }
    __syncthreads();
#pragma unroll
    for (int ks = 0; ks < 2; ++ks) {
      frag8 af[2], bfr[4];
#pragma unroll
      for (int mi = 0; mi < 2; ++mi) {
        int row = wm * 32 + mi * 16 + (lane & 15);
        int off = (ks * 64 + ((lane >> 4) << 4)) ^ ((row & 7) << 4);
        af[mi] = *(const frag8*)((const char*)As + row * 128 + off);
      }
#pragma unroll
      for (int ni = 0; ni < 4; ++ni) {
        int row = wn * 64 + ni * 16 + (lane & 15);
        int off = (ks * 64 + ((lane >> 4) << 4)) ^ ((row & 7) << 4);
        bfr[ni] = *(const frag8*)((const char*)Bs + row * 128 + off);
      }
#pragma unroll
      for (int mi = 0; mi < 2; ++mi)
#pragma unroll
        for (int ni = 0; ni < 4; ++ni)
          acc[mi][ni] = mfma16(af[mi], bfr[ni], acc[mi][ni]);
    }
  }
  const int r0 = (lane >> 4) << 2;
#pragma unroll
  for (int ni = 0; ni < 4; ++ni) {
    const int gc = nbase + wn * 64 + ni * 16 + (lane & 15);
    const float bi = bias[gc];
#pragma unroll
    for (int mi = 0; mi < 2; ++mi)
#pragma unroll
      for (int r = 0; r < 4; ++r) {
        const int gr = mbase + wm * 32 + mi * 16 + r0 + r;
        out[(size_t)gr * 1024 + gc] = acc[mi][ni][r] + bi;
      }
  }
}

extern "C" void kernel_launch(void* const* d_in, const int* in_sizes, int n_in,
                              void* d_out, int out_size, void* d_ws, size_t ws_size,
                              hipStream_t stream) {
  const float* x    = (const float*)d_in[0];
  const float* mask = (const float*)d_in[1];
  const float* wi   = (const float*)d_in[2];
  const float* bi   = (const float*)d_in[3];
  const float* wo   = (const float*)d_in[4];
  const float* bo   = (const float*)d_in[5];
  const float* la   = (const float*)d_in[6];
  const float* lb   = (const float*)d_in[7];
  float* out = (float*)d_out;

  char* ws = (char*)d_ws;
  u16* x_bf  = (u16*)ws;              ws += (size_t)4096 * 1024 * 2;
  u16* w_bf  = (u16*)ws;              ws += (size_t)3072 * 1024 * 2;
  u16* wo_bf = (u16*)ws;              ws += (size_t)1024 * 1024 * 2;
  u16* q_ws  = (u16*)ws;              ws += (size_t)4096 * 1024 * 2;
  u16* k_ws  = (u16*)ws;              ws += (size_t)4096 * 1024 * 2;
  u16* v_t   = (u16*)ws;              ws += (size_t)4096 * 1024 * 2;
  u16* a_ws  = (u16*)ws;              ws += (size_t)4096 * 1024 * 2;
  u16* m_bf  = (u16*)ws;              ws += (size_t)4096 * 2048 * 2;
  float* xa  = (float*)ws;            ws += (size_t)4096 * 8 * 4;

  k_prep<<<dim3(7168), dim3(256), 0, stream>>>(wi, w_bf, wo, wo_bf,
                                               x, la, xa, x_bf, mask, m_bf);
  k_gemm_qkv<<<dim3(24, 32), dim3(256), 0, stream>>>(x_bf, w_bf, bi, xa, lb,
                                                     q_ws, k_ws, v_t);
  k_attn<<<dim3(512), dim3(256), 0, stream>>>(q_ws, k_ws, v_t, m_bf, a_ws);
  k_gemm_out<<<dim3(8, 64), dim3(256), 0, stream>>>(a_ws, wo_bf, bo, out);
}